// Round 1
// baseline (1015.509 us; speedup 1.0000x reference)
//
#include <hip/hip_runtime.h>
#include <hip/hip_bf16.h>

// Problem constants
#define BB 8
#define HH 56
#define WW 56
#define CC 384
#define NHD 6
#define DD 64
#define HK 28
#define WK 28
#define NQ (HH*WW)       // 3136
#define NKV (HK*WK)      // 784
#define NTOK (BB*NQ)     // 25088
#define NTOKKV (BB*NKV)  // 6272
#define BN_EPS 1e-5f

// ---------------- depthwise conv + BN, stride 1 (q path) ----------------
__global__ __launch_bounds__(256) void dw_bn_s1(
    const float* __restrict__ in, const float* __restrict__ w,
    const float* __restrict__ bns, const float* __restrict__ bnb,
    const float* __restrict__ bnm, const float* __restrict__ bnv,
    float* __restrict__ out) {
  int idx = blockIdx.x * 256 + threadIdx.x;      // < NTOK*96
  int pix = idx / 96;
  int c = (idx % 96) * 4;
  int b = pix / (HH * WW);
  int p = pix % (HH * WW);
  int y = p / WW, x = p % WW;
  float ax = 0.f, ay = 0.f, az = 0.f, aw = 0.f;
#pragma unroll
  for (int kh = 0; kh < 3; ++kh) {
    int iy = y + kh - 1;
    if ((unsigned)iy >= (unsigned)HH) continue;
#pragma unroll
    for (int kw = 0; kw < 3; ++kw) {
      int ix = x + kw - 1;
      if ((unsigned)ix >= (unsigned)WW) continue;
      const float4 v = *(const float4*)(in + (((size_t)(b * HH + iy) * WW + ix) * CC + c));
      const float4 wk = *(const float4*)(w + ((kh * 3 + kw) * CC + c));
      ax = fmaf(v.x, wk.x, ax); ay = fmaf(v.y, wk.y, ay);
      az = fmaf(v.z, wk.z, az); aw = fmaf(v.w, wk.w, aw);
    }
  }
  const float4 s = *(const float4*)(bns + c);
  const float4 bi = *(const float4*)(bnb + c);
  const float4 m = *(const float4*)(bnm + c);
  const float4 va = *(const float4*)(bnv + c);
  float4 r;
  float g;
  g = s.x * rsqrtf(va.x + BN_EPS); r.x = fmaf(ax - m.x, g, bi.x);
  g = s.y * rsqrtf(va.y + BN_EPS); r.y = fmaf(ay - m.y, g, bi.y);
  g = s.z * rsqrtf(va.z + BN_EPS); r.z = fmaf(az - m.z, g, bi.z);
  g = s.w * rsqrtf(va.w + BN_EPS); r.w = fmaf(aw - m.w, g, bi.w);
  *(float4*)(out + (size_t)pix * CC + c) = r;
}

// -------- fused depthwise conv + BN, stride 2, k and v from same input --------
__global__ __launch_bounds__(256) void dw_bn_s2_kv(
    const float* __restrict__ in,
    const float* __restrict__ wk_, const float* __restrict__ kbs, const float* __restrict__ kbb,
    const float* __restrict__ kbm, const float* __restrict__ kbv,
    const float* __restrict__ wv_, const float* __restrict__ vbs, const float* __restrict__ vbb,
    const float* __restrict__ vbm, const float* __restrict__ vbv,
    float* __restrict__ outk, float* __restrict__ outv) {
  int idx = blockIdx.x * 256 + threadIdx.x;      // < NTOKKV*96
  int pix = idx / 96;
  int c = (idx % 96) * 4;
  int b = pix / (HK * WK);
  int p = pix % (HK * WK);
  int oy = p / WK, ox = p % WK;
  float kx = 0, ky = 0, kz = 0, kw4 = 0;
  float vx = 0, vy = 0, vz = 0, vw4 = 0;
#pragma unroll
  for (int kh = 0; kh < 3; ++kh) {
    int iy = oy * 2 + kh;                        // pad_lo = 0 for SAME stride-2 (56->28, k=3)
    if (iy >= HH) continue;
#pragma unroll
    for (int kwi = 0; kwi < 3; ++kwi) {
      int ix = ox * 2 + kwi;
      if (ix >= WW) continue;
      const float4 v = *(const float4*)(in + (((size_t)(b * HH + iy) * WW + ix) * CC + c));
      const float4 a = *(const float4*)(wk_ + ((kh * 3 + kwi) * CC + c));
      const float4 bq = *(const float4*)(wv_ + ((kh * 3 + kwi) * CC + c));
      kx = fmaf(v.x, a.x, kx); ky = fmaf(v.y, a.y, ky);
      kz = fmaf(v.z, a.z, kz); kw4 = fmaf(v.w, a.w, kw4);
      vx = fmaf(v.x, bq.x, vx); vy = fmaf(v.y, bq.y, vy);
      vz = fmaf(v.z, bq.z, vz); vw4 = fmaf(v.w, bq.w, vw4);
    }
  }
  {
    const float4 s = *(const float4*)(kbs + c);
    const float4 bi = *(const float4*)(kbb + c);
    const float4 m = *(const float4*)(kbm + c);
    const float4 va = *(const float4*)(kbv + c);
    float4 r; float g;
    g = s.x * rsqrtf(va.x + BN_EPS); r.x = fmaf(kx - m.x, g, bi.x);
    g = s.y * rsqrtf(va.y + BN_EPS); r.y = fmaf(ky - m.y, g, bi.y);
    g = s.z * rsqrtf(va.z + BN_EPS); r.z = fmaf(kz - m.z, g, bi.z);
    g = s.w * rsqrtf(va.w + BN_EPS); r.w = fmaf(kw4 - m.w, g, bi.w);
    *(float4*)(outk + (size_t)pix * CC + c) = r;
  }
  {
    const float4 s = *(const float4*)(vbs + c);
    const float4 bi = *(const float4*)(vbb + c);
    const float4 m = *(const float4*)(vbm + c);
    const float4 va = *(const float4*)(vbv + c);
    float4 r; float g;
    g = s.x * rsqrtf(va.x + BN_EPS); r.x = fmaf(vx - m.x, g, bi.x);
    g = s.y * rsqrtf(va.y + BN_EPS); r.y = fmaf(vy - m.y, g, bi.y);
    g = s.z * rsqrtf(va.z + BN_EPS); r.z = fmaf(vz - m.z, g, bi.z);
    g = s.w * rsqrtf(va.w + BN_EPS); r.w = fmaf(vw4 - m.w, g, bi.w);
    *(float4*)(outv + (size_t)pix * CC + c) = r;
  }
}

// ------------- fp32 tiled GEMM: C[M,384] = scale * A[M,384] @ Bw[384,384] -------------
// grid = (M/64, 6), block = 256, each thread computes 4x4.
__global__ __launch_bounds__(256) void gemm384(
    const float* __restrict__ A, const float* __restrict__ Bw,
    float* __restrict__ Cout, float scale) {
  __shared__ float As[16][72];   // [k][row], padded
  __shared__ float Bs[16][72];   // [k][col], padded
  const int row0 = blockIdx.x * 64;
  const int col0 = blockIdx.y * 64;
  const int tid = threadIdx.x;
  const int tx = tid & 15, ty = tid >> 4;
  const int arow = tid >> 2, akq = tid & 3;
  const int brow = tid >> 4, bc4 = tid & 15;
  float acc[4][4] = {};
  for (int k0 = 0; k0 < 384; k0 += 16) {
    const float4 a = *(const float4*)(A + (size_t)(row0 + arow) * 384 + k0 + akq * 4);
    const float4 bv = *(const float4*)(Bw + (size_t)(k0 + brow) * 384 + col0 + bc4 * 4);
    __syncthreads();
    As[akq * 4 + 0][arow] = a.x;
    As[akq * 4 + 1][arow] = a.y;
    As[akq * 4 + 2][arow] = a.z;
    As[akq * 4 + 3][arow] = a.w;
    *(float4*)&Bs[brow][bc4 * 4] = bv;
    __syncthreads();
#pragma unroll
    for (int kk = 0; kk < 16; ++kk) {
      const float4 av = *(const float4*)&As[kk][ty * 4];
      const float4 bvv = *(const float4*)&Bs[kk][tx * 4];
      acc[0][0] = fmaf(av.x, bvv.x, acc[0][0]);
      acc[0][1] = fmaf(av.x, bvv.y, acc[0][1]);
      acc[0][2] = fmaf(av.x, bvv.z, acc[0][2]);
      acc[0][3] = fmaf(av.x, bvv.w, acc[0][3]);
      acc[1][0] = fmaf(av.y, bvv.x, acc[1][0]);
      acc[1][1] = fmaf(av.y, bvv.y, acc[1][1]);
      acc[1][2] = fmaf(av.y, bvv.z, acc[1][2]);
      acc[1][3] = fmaf(av.y, bvv.w, acc[1][3]);
      acc[2][0] = fmaf(av.z, bvv.x, acc[2][0]);
      acc[2][1] = fmaf(av.z, bvv.y, acc[2][1]);
      acc[2][2] = fmaf(av.z, bvv.z, acc[2][2]);
      acc[2][3] = fmaf(av.z, bvv.w, acc[2][3]);
      acc[3][0] = fmaf(av.w, bvv.x, acc[3][0]);
      acc[3][1] = fmaf(av.w, bvv.y, acc[3][1]);
      acc[3][2] = fmaf(av.w, bvv.z, acc[3][2]);
      acc[3][3] = fmaf(av.w, bvv.w, acc[3][3]);
    }
  }
#pragma unroll
  for (int i = 0; i < 4; ++i) {
    float4 o;
    o.x = acc[i][0] * scale; o.y = acc[i][1] * scale;
    o.z = acc[i][2] * scale; o.w = acc[i][3] * scale;
    *(float4*)(Cout + (size_t)(row0 + ty * 4 + i) * 384 + col0 + tx * 4) = o;
  }
}

// ------------- flash-style fp32 attention -------------
// grid = B*NH*(3136/32) blocks; block = 256 (32 q-rows x 8 lanes each)
__global__ __launch_bounds__(256) void attn_fwd(
    const float* __restrict__ qp, const float* __restrict__ kp,
    const float* __restrict__ vp, float* __restrict__ op) {
  __shared__ float Qs[32][68];
  __shared__ float Ks[64][68];
  __shared__ float Vs[64][68];
  __shared__ float Ps[32][68];
  const int bid = blockIdx.x;
  const int qt = bid % 98;
  const int bh = bid / 98;
  const int h = bh % NHD, b = bh / NHD;
  const int tid = threadIdx.x;
  const int r = tid >> 3, cc = tid & 7;
  // load Q tile (already scaled by 0.125 in pw GEMM)
  {
    const int row = tid >> 3, part = tid & 7;
    const float* src = qp + ((size_t)(b * NQ + qt * 32 + row)) * CC + h * DD + part * 8;
    *(float4*)&Qs[row][part * 8] = *(const float4*)src;
    *(float4*)&Qs[row][part * 8 + 4] = *(const float4*)(src + 4);
  }
  float mrun = -1e30f, lsum = 0.f;
  float4 o0 = {0, 0, 0, 0}, o1 = {0, 0, 0, 0};
  const int krow = tid >> 2, kq = tid & 3;
  for (int t0 = 0; t0 < NKV; t0 += 64) {
    __syncthreads();   // prev PV done (and Q visible on iter 0 via next barrier)
    const int j = t0 + krow;
    if (j < NKV) {
      const float* ks = kp + ((size_t)(b * NKV + j)) * CC + h * DD + kq * 16;
      const float* vs = vp + ((size_t)(b * NKV + j)) * CC + h * DD + kq * 16;
#pragma unroll
      for (int q4 = 0; q4 < 4; ++q4) {
        *(float4*)&Ks[krow][kq * 16 + q4 * 4] = *(const float4*)(ks + q4 * 4);
        *(float4*)&Vs[krow][kq * 16 + q4 * 4] = *(const float4*)(vs + q4 * 4);
      }
    } else {
      const float4 z = {0, 0, 0, 0};
#pragma unroll
      for (int q4 = 0; q4 < 4; ++q4) {
        *(float4*)&Ks[krow][kq * 16 + q4 * 4] = z;
        *(float4*)&Vs[krow][kq * 16 + q4 * 4] = z;
      }
    }
    __syncthreads();
    // S tile: each thread: rows r, kv j = cc + 8m
    float s[8];
#pragma unroll
    for (int m = 0; m < 8; ++m) s[m] = 0.f;
#pragma unroll
    for (int d4 = 0; d4 < 16; ++d4) {
      const float4 q4 = *(const float4*)&Qs[r][d4 * 4];
#pragma unroll
      for (int m = 0; m < 8; ++m) {
        const float4 k4 = *(const float4*)&Ks[cc + 8 * m][d4 * 4];
        s[m] = fmaf(q4.x, k4.x, fmaf(q4.y, k4.y, fmaf(q4.z, k4.z, fmaf(q4.w, k4.w, s[m]))));
      }
    }
    if (t0 + 64 > NKV) {
#pragma unroll
      for (int m = 0; m < 8; ++m)
        if (t0 + cc + 8 * m >= NKV) s[m] = -1e30f;
    }
    // online softmax over this tile
    float mt = s[0];
#pragma unroll
    for (int m = 1; m < 8; ++m) mt = fmaxf(mt, s[m]);
    mt = fmaxf(mt, __shfl_xor(mt, 1));
    mt = fmaxf(mt, __shfl_xor(mt, 2));
    mt = fmaxf(mt, __shfl_xor(mt, 4));
    const float mnew = fmaxf(mrun, mt);
    const float corr = __expf(mrun - mnew);
    float ps = 0.f;
#pragma unroll
    for (int m = 0; m < 8; ++m) {
      const float pv = __expf(s[m] - mnew);
      ps += pv;
      Ps[r][cc + 8 * m] = pv;
    }
    ps += __shfl_xor(ps, 1);
    ps += __shfl_xor(ps, 2);
    ps += __shfl_xor(ps, 4);
    lsum = lsum * corr + ps;
    mrun = mnew;
    o0.x *= corr; o0.y *= corr; o0.z *= corr; o0.w *= corr;
    o1.x *= corr; o1.y *= corr; o1.z *= corr; o1.w *= corr;
    __syncthreads();
    // PV: thread owns d = cc*8 .. cc*8+7 for row r
#pragma unroll 8
    for (int jj = 0; jj < 64; ++jj) {
      const float pj = Ps[r][jj];
      const float4 v0 = *(const float4*)&Vs[jj][cc * 8];
      const float4 v1 = *(const float4*)&Vs[jj][cc * 8 + 4];
      o0.x = fmaf(pj, v0.x, o0.x); o0.y = fmaf(pj, v0.y, o0.y);
      o0.z = fmaf(pj, v0.z, o0.z); o0.w = fmaf(pj, v0.w, o0.w);
      o1.x = fmaf(pj, v1.x, o1.x); o1.y = fmaf(pj, v1.y, o1.y);
      o1.z = fmaf(pj, v1.z, o1.z); o1.w = fmaf(pj, v1.w, o1.w);
    }
  }
  const float inv = 1.0f / lsum;
  float* dst = op + ((size_t)(b * NQ + qt * 32 + r)) * CC + h * DD + cc * 8;
  float4 w0, w1;
  w0.x = o0.x * inv; w0.y = o0.y * inv; w0.z = o0.z * inv; w0.w = o0.w * inv;
  w1.x = o1.x * inv; w1.y = o1.y * inv; w1.z = o1.z * inv; w1.w = o1.w * inv;
  *(float4*)dst = w0;
  *(float4*)(dst + 4) = w1;
}

extern "C" void kernel_launch(void* const* d_in, const int* in_sizes, int n_in,
                              void* d_out, int out_size, void* d_ws, size_t ws_size,
                              hipStream_t stream) {
  const float* inputs_q  = (const float*)d_in[0];
  const float* inputs_kv = (const float*)d_in[1];
  const float* out_kern  = (const float*)d_in[2];
  const float* q_dwk = (const float*)d_in[3];
  const float* q_bs  = (const float*)d_in[4];
  const float* q_bb  = (const float*)d_in[5];
  const float* q_bm  = (const float*)d_in[6];
  const float* q_bv  = (const float*)d_in[7];
  const float* q_pwk = (const float*)d_in[8];
  const float* k_dwk = (const float*)d_in[9];
  const float* k_bs  = (const float*)d_in[10];
  const float* k_bb  = (const float*)d_in[11];
  const float* k_bm  = (const float*)d_in[12];
  const float* k_bv  = (const float*)d_in[13];
  const float* k_pwk = (const float*)d_in[14];
  const float* v_dwk = (const float*)d_in[15];
  const float* v_bs  = (const float*)d_in[16];
  const float* v_bb  = (const float*)d_in[17];
  const float* v_bm  = (const float*)d_in[18];
  const float* v_bv  = (const float*)d_in[19];
  const float* v_pwk = (const float*)d_in[20];

  float* ws = (float*)d_ws;
  // workspace layout (floats)
  const size_t Q_DWBN = 0;                      // 25088*384
  const size_t K_DWBN = 9633792;                // 6272*384
  const size_t V_DWBN = 12042240;
  const size_t Q_PW   = 14450688;               // 25088*384
  const size_t K_PW   = 24084480;
  const size_t V_PW   = 26492928;               // end: 28901376 floats (~115.6 MB)
  const size_t O_BUF  = 0;                      // alias Q_DWBN (dead after q pw GEMM)

  // 1. depthwise+BN q (stride 1)
  dw_bn_s1<<<9408, 256, 0, stream>>>(inputs_q, q_dwk, q_bs, q_bb, q_bm, q_bv, ws + Q_DWBN);
  // 2. depthwise+BN k,v fused (stride 2)
  dw_bn_s2_kv<<<2352, 256, 0, stream>>>(inputs_kv,
      k_dwk, k_bs, k_bb, k_bm, k_bv,
      v_dwk, v_bs, v_bb, v_bm, v_bv,
      ws + K_DWBN, ws + V_DWBN);
  // 3. pointwise GEMMs (q folded with 1/sqrt(64))
  gemm384<<<dim3(392, 6), 256, 0, stream>>>(ws + Q_DWBN, q_pwk, ws + Q_PW, 0.125f);
  gemm384<<<dim3(98, 6), 256, 0, stream>>>(ws + K_DWBN, k_pwk, ws + K_PW, 1.0f);
  gemm384<<<dim3(98, 6), 256, 0, stream>>>(ws + V_DWBN, v_pwk, ws + V_PW, 1.0f);
  // 4. attention
  attn_fwd<<<8 * NHD * 98, 256, 0, stream>>>(ws + Q_PW, ws + K_PW, ws + V_PW, ws + O_BUF);
  // 5. output projection
  gemm384<<<dim3(392, 6), 256, 0, stream>>>(ws + O_BUF, out_kern, (float*)d_out, 1.0f);
}

// Round 2
// 475.367 us; speedup vs baseline: 2.1363x; 2.1363x over previous
//
#include <hip/hip_runtime.h>
#include <hip/hip_bf16.h>
#include <hip/hip_fp16.h>

// Problem constants
#define BB 8
#define HH 56
#define WW 56
#define CC 384
#define NHD 6
#define DD 64
#define HK 28
#define WK 28
#define NQ (HH*WW)       // 3136
#define NKV (HK*WK)      // 784
#define NTOK (BB*NQ)     // 25088
#define NTOKKV (BB*NKV)  // 6272
#define BN_EPS 1e-5f

typedef _Float16 f16;
typedef _Float16 f16x4 __attribute__((ext_vector_type(4)));
typedef _Float16 f16x8 __attribute__((ext_vector_type(8)));
typedef float f32x4 __attribute__((ext_vector_type(4)));

// ---------------- depthwise conv + BN, stride 1 (q path) ----------------
__global__ __launch_bounds__(256) void dw_bn_s1(
    const float* __restrict__ in, const float* __restrict__ w,
    const float* __restrict__ bns, const float* __restrict__ bnb,
    const float* __restrict__ bnm, const float* __restrict__ bnv,
    float* __restrict__ out) {
  int idx = blockIdx.x * 256 + threadIdx.x;      // < NTOK*96
  int pix = idx / 96;
  int c = (idx % 96) * 4;
  int b = pix / (HH * WW);
  int p = pix % (HH * WW);
  int y = p / WW, x = p % WW;
  float ax = 0.f, ay = 0.f, az = 0.f, aw = 0.f;
#pragma unroll
  for (int kh = 0; kh < 3; ++kh) {
    int iy = y + kh - 1;
    if ((unsigned)iy >= (unsigned)HH) continue;
#pragma unroll
    for (int kw = 0; kw < 3; ++kw) {
      int ix = x + kw - 1;
      if ((unsigned)ix >= (unsigned)WW) continue;
      const float4 v = *(const float4*)(in + (((size_t)(b * HH + iy) * WW + ix) * CC + c));
      const float4 wk = *(const float4*)(w + ((kh * 3 + kw) * CC + c));
      ax = fmaf(v.x, wk.x, ax); ay = fmaf(v.y, wk.y, ay);
      az = fmaf(v.z, wk.z, az); aw = fmaf(v.w, wk.w, aw);
    }
  }
  const float4 s = *(const float4*)(bns + c);
  const float4 bi = *(const float4*)(bnb + c);
  const float4 m = *(const float4*)(bnm + c);
  const float4 va = *(const float4*)(bnv + c);
  float4 r;
  float g;
  g = s.x * rsqrtf(va.x + BN_EPS); r.x = fmaf(ax - m.x, g, bi.x);
  g = s.y * rsqrtf(va.y + BN_EPS); r.y = fmaf(ay - m.y, g, bi.y);
  g = s.z * rsqrtf(va.z + BN_EPS); r.z = fmaf(az - m.z, g, bi.z);
  g = s.w * rsqrtf(va.w + BN_EPS); r.w = fmaf(aw - m.w, g, bi.w);
  *(float4*)(out + (size_t)pix * CC + c) = r;
}

// -------- fused depthwise conv + BN, stride 2, k and v from same input --------
__global__ __launch_bounds__(256) void dw_bn_s2_kv(
    const float* __restrict__ in,
    const float* __restrict__ wk_, const float* __restrict__ kbs, const float* __restrict__ kbb,
    const float* __restrict__ kbm, const float* __restrict__ kbv,
    const float* __restrict__ wv_, const float* __restrict__ vbs, const float* __restrict__ vbb,
    const float* __restrict__ vbm, const float* __restrict__ vbv,
    float* __restrict__ outk, float* __restrict__ outv) {
  int idx = blockIdx.x * 256 + threadIdx.x;      // < NTOKKV*96
  int pix = idx / 96;
  int c = (idx % 96) * 4;
  int b = pix / (HK * WK);
  int p = pix % (HK * WK);
  int oy = p / WK, ox = p % WK;
  float kx = 0, ky = 0, kz = 0, kw4 = 0;
  float vx = 0, vy = 0, vz = 0, vw4 = 0;
#pragma unroll
  for (int kh = 0; kh < 3; ++kh) {
    int iy = oy * 2 + kh;
    if (iy >= HH) continue;
#pragma unroll
    for (int kwi = 0; kwi < 3; ++kwi) {
      int ix = ox * 2 + kwi;
      if (ix >= WW) continue;
      const float4 v = *(const float4*)(in + (((size_t)(b * HH + iy) * WW + ix) * CC + c));
      const float4 a = *(const float4*)(wk_ + ((kh * 3 + kwi) * CC + c));
      const float4 bq = *(const float4*)(wv_ + ((kh * 3 + kwi) * CC + c));
      kx = fmaf(v.x, a.x, kx); ky = fmaf(v.y, a.y, ky);
      kz = fmaf(v.z, a.z, kz); kw4 = fmaf(v.w, a.w, kw4);
      vx = fmaf(v.x, bq.x, vx); vy = fmaf(v.y, bq.y, vy);
      vz = fmaf(v.z, bq.z, vz); vw4 = fmaf(v.w, bq.w, vw4);
    }
  }
  {
    const float4 s = *(const float4*)(kbs + c);
    const float4 bi = *(const float4*)(kbb + c);
    const float4 m = *(const float4*)(kbm + c);
    const float4 va = *(const float4*)(kbv + c);
    float4 r; float g;
    g = s.x * rsqrtf(va.x + BN_EPS); r.x = fmaf(kx - m.x, g, bi.x);
    g = s.y * rsqrtf(va.y + BN_EPS); r.y = fmaf(ky - m.y, g, bi.y);
    g = s.z * rsqrtf(va.z + BN_EPS); r.z = fmaf(kz - m.z, g, bi.z);
    g = s.w * rsqrtf(va.w + BN_EPS); r.w = fmaf(kw4 - m.w, g, bi.w);
    *(float4*)(outk + (size_t)pix * CC + c) = r;
  }
  {
    const float4 s = *(const float4*)(vbs + c);
    const float4 bi = *(const float4*)(vbb + c);
    const float4 m = *(const float4*)(vbm + c);
    const float4 va = *(const float4*)(vbv + c);
    float4 r; float g;
    g = s.x * rsqrtf(va.x + BN_EPS); r.x = fmaf(vx - m.x, g, bi.x);
    g = s.y * rsqrtf(va.y + BN_EPS); r.y = fmaf(vy - m.y, g, bi.y);
    g = s.z * rsqrtf(va.z + BN_EPS); r.z = fmaf(vz - m.z, g, bi.z);
    g = s.w * rsqrtf(va.w + BN_EPS); r.w = fmaf(vw4 - m.w, g, bi.w);
    *(float4*)(outv + (size_t)pix * CC + c) = r;
  }
}

// ------------- fp32 tiled GEMM: C[M,384] = scale * A[M,384] @ Bw[384,384] -------------
// OMODE 0: fp32 row-major out; OMODE 1: f16 row-major out.
template <int OMODE>
__global__ __launch_bounds__(256) void gemm384(
    const float* __restrict__ A, const float* __restrict__ Bw,
    float* __restrict__ Cout, f16* __restrict__ Ch, float scale) {
  __shared__ float As[16][72];
  __shared__ float Bs[16][72];
  const int row0 = blockIdx.x * 64;
  const int col0 = blockIdx.y * 64;
  const int tid = threadIdx.x;
  const int tx = tid & 15, ty = tid >> 4;
  const int arow = tid >> 2, akq = tid & 3;
  const int brow = tid >> 4, bc4 = tid & 15;
  float acc[4][4] = {};
  for (int k0 = 0; k0 < 384; k0 += 16) {
    const float4 a = *(const float4*)(A + (size_t)(row0 + arow) * 384 + k0 + akq * 4);
    const float4 bv = *(const float4*)(Bw + (size_t)(k0 + brow) * 384 + col0 + bc4 * 4);
    __syncthreads();
    As[akq * 4 + 0][arow] = a.x;
    As[akq * 4 + 1][arow] = a.y;
    As[akq * 4 + 2][arow] = a.z;
    As[akq * 4 + 3][arow] = a.w;
    *(float4*)&Bs[brow][bc4 * 4] = bv;
    __syncthreads();
#pragma unroll
    for (int kk = 0; kk < 16; ++kk) {
      const float4 av = *(const float4*)&As[kk][ty * 4];
      const float4 bvv = *(const float4*)&Bs[kk][tx * 4];
      acc[0][0] = fmaf(av.x, bvv.x, acc[0][0]);
      acc[0][1] = fmaf(av.x, bvv.y, acc[0][1]);
      acc[0][2] = fmaf(av.x, bvv.z, acc[0][2]);
      acc[0][3] = fmaf(av.x, bvv.w, acc[0][3]);
      acc[1][0] = fmaf(av.y, bvv.x, acc[1][0]);
      acc[1][1] = fmaf(av.y, bvv.y, acc[1][1]);
      acc[1][2] = fmaf(av.y, bvv.z, acc[1][2]);
      acc[1][3] = fmaf(av.y, bvv.w, acc[1][3]);
      acc[2][0] = fmaf(av.z, bvv.x, acc[2][0]);
      acc[2][1] = fmaf(av.z, bvv.y, acc[2][1]);
      acc[2][2] = fmaf(av.z, bvv.z, acc[2][2]);
      acc[2][3] = fmaf(av.z, bvv.w, acc[2][3]);
      acc[3][0] = fmaf(av.w, bvv.x, acc[3][0]);
      acc[3][1] = fmaf(av.w, bvv.y, acc[3][1]);
      acc[3][2] = fmaf(av.w, bvv.z, acc[3][2]);
      acc[3][3] = fmaf(av.w, bvv.w, acc[3][3]);
    }
  }
#pragma unroll
  for (int i = 0; i < 4; ++i) {
    if (OMODE == 0) {
      float4 o;
      o.x = acc[i][0] * scale; o.y = acc[i][1] * scale;
      o.z = acc[i][2] * scale; o.w = acc[i][3] * scale;
      *(float4*)(Cout + (size_t)(row0 + ty * 4 + i) * 384 + col0 + tx * 4) = o;
    } else {
      f16x4 o;
      o[0] = (f16)(acc[i][0] * scale); o[1] = (f16)(acc[i][1] * scale);
      o[2] = (f16)(acc[i][2] * scale); o[3] = (f16)(acc[i][3] * scale);
      *(f16x4*)(Ch + (size_t)(row0 + ty * 4 + i) * 384 + col0 + tx * 4) = o;
    }
  }
}

// ------------- per-batch transpose: in [b*784+kv][384] -> out [b*384+c][784] -------------
__global__ __launch_bounds__(256) void transpose_f16(
    const f16* __restrict__ in, f16* __restrict__ out) {
  __shared__ f16 t[32][33];
  const int b = blockIdx.z;
  const int kv0 = blockIdx.x * 32, c0 = blockIdx.y * 32;
  const int x = threadIdx.x & 31, y = threadIdx.x >> 5;  // 32 x 8
#pragma unroll
  for (int i = 0; i < 4; ++i) {
    int row = y + i * 8;                  // kv within tile
    int kv = kv0 + row;
    if (kv < NKV) t[row][x] = in[((size_t)b * NKV + kv) * 384 + c0 + x];
  }
  __syncthreads();
#pragma unroll
  for (int i = 0; i < 4; ++i) {
    int row = y + i * 8;                  // c within tile
    if (kv0 + x < NKV)
      out[((size_t)b * 384 + c0 + row) * NKV + kv0 + x] = t[x][row];
  }
}

// ------------- f16 MFMA flash attention -------------
// grid = B*NH*(3136/64); block = 256 (4 waves x 16 q-rows).
// qp [25088][384] f16 (pre-scaled 0.125), kp [6272][384] f16,
// vt [8*384][784] f16 (transposed per batch), op [25088][384] fp32.
#define KVT 32
__global__ __launch_bounds__(256) void attn_mfma(
    const f16* __restrict__ qp, const f16* __restrict__ kp,
    const f16* __restrict__ vt, float* __restrict__ op) {
  __shared__ f16 Ks[KVT * 64];            // chunk-swizzled: row kv, chunk j stored at j^(kv&7)
  __shared__ f16 Ps[4][16 * 36];          // per-wave P, row stride 36 halves
  const int bid = blockIdx.x;
  const int qt = bid % 49;
  const int bh = bid / 49;
  const int h = bh % NHD, b = bh / NHD;
  const int tid = threadIdx.x;
  const int wave = tid >> 6, lane = tid & 63;
  const int c = lane & 15, g = lane >> 4;

  // Q A-frags: rows = qt*64 + wave*16 + c, k-dim = kh*32 + g*8 + j
  const size_t qrow = (size_t)b * NQ + qt * 64 + wave * 16 + c;
  f16x8 qa0 = *(const f16x8*)(qp + qrow * 384 + h * 64 + g * 8);
  f16x8 qa1 = *(const f16x8*)(qp + qrow * 384 + h * 64 + 32 + g * 8);

  // K staging: thread t fills LDS halves [t*8, t*8+8) = row t>>3, stored chunk t&7
  const int st_kv = tid >> 3;
  const int st_l = (tid & 7) ^ (st_kv & 7);    // logical chunk to fetch

  f32x4 o[4] = {};
  float mrun[4], lsum[4];
#pragma unroll
  for (int r = 0; r < 4; ++r) { mrun[r] = -1e30f; lsum[r] = 0.f; }

  const f16* vbase = vt + ((size_t)b * 384 + h * 64) * NKV;
  f16* pw = &Ps[wave][0];

  for (int t0 = 0; t0 < NKV; t0 += KVT) {
    __syncthreads();
    {
      int kv = t0 + st_kv;
      if (kv > NKV - 1) kv = NKV - 1;          // clamp tail (garbage masked later)
      const f16* gsrc = kp + ((size_t)b * NKV + kv) * 384 + h * 64 + st_l * 8;
      __builtin_amdgcn_global_load_lds(
          (const __attribute__((address_space(1))) void*)gsrc,
          (__attribute__((address_space(3))) void*)(Ks + wave * 512),
          16, 0, 0);
    }
    __syncthreads();

    // S = Q K^T : 2 col-tiles x 2 k-halves
    f32x4 s0 = {0.f, 0.f, 0.f, 0.f}, s1 = {0.f, 0.f, 0.f, 0.f};
#pragma unroll
    for (int kh = 0; kh < 2; ++kh) {
      const f16x8 qa = kh ? qa1 : qa0;
      {
        int row = c;
        int ch = (kh * 4 + g) ^ (row & 7);
        f16x8 kb = *(const f16x8*)(Ks + row * 64 + ch * 8);
        s0 = __builtin_amdgcn_mfma_f32_16x16x32_f16(qa, kb, s0, 0, 0, 0);
      }
      {
        int row = 16 + c;
        int ch = (kh * 4 + g) ^ (row & 7);
        f16x8 kb = *(const f16x8*)(Ks + row * 64 + ch * 8);
        s1 = __builtin_amdgcn_mfma_f32_16x16x32_f16(qa, kb, s1, 0, 0, 0);
      }
    }
    // tail mask (only last tile: kv = t0+16+c >= 784 for ct=1)
    if (t0 + KVT > NKV) {
#pragma unroll
      for (int r = 0; r < 4; ++r) {
        if (t0 + c >= NKV) s0[r] = -1e30f;
        if (t0 + 16 + c >= NKV) s1[r] = -1e30f;
      }
    }

    // online softmax; lane holds S[q = g*4+r][kv = ct*16 + c]
    float corr[4];
#pragma unroll
    for (int r = 0; r < 4; ++r) {
      float mt = fmaxf(s0[r], s1[r]);
      mt = fmaxf(mt, __shfl_xor(mt, 1));
      mt = fmaxf(mt, __shfl_xor(mt, 2));
      mt = fmaxf(mt, __shfl_xor(mt, 4));
      mt = fmaxf(mt, __shfl_xor(mt, 8));
      const float mnew = fmaxf(mrun[r], mt);
      corr[r] = __expf(mrun[r] - mnew);
      mrun[r] = mnew;
      const float p0 = __expf(s0[r] - mnew);
      const float p1 = __expf(s1[r] - mnew);
      s0[r] = p0; s1[r] = p1;
      float ps = p0 + p1;
      ps += __shfl_xor(ps, 1);
      ps += __shfl_xor(ps, 2);
      ps += __shfl_xor(ps, 4);
      ps += __shfl_xor(ps, 8);
      lsum[r] = lsum[r] * corr[r] + ps;
    }
#pragma unroll
    for (int dt = 0; dt < 4; ++dt)
#pragma unroll
      for (int r = 0; r < 4; ++r) o[dt][r] *= corr[r];

    // P -> LDS (f16), row stride 36
#pragma unroll
    for (int r = 0; r < 4; ++r) {
      const int row = g * 4 + r;
      pw[row * 36 + c] = (f16)s0[r];
      pw[row * 36 + 16 + c] = (f16)s1[r];
    }
    // P A-frag: lane holds P[q = c][kv = g*8 + j]
    f16x4 plo = *(const f16x4*)(pw + c * 36 + g * 8);
    f16x4 phi = *(const f16x4*)(pw + c * 36 + g * 8 + 4);
    f16x8 pa = __builtin_shufflevector(plo, phi, 0, 1, 2, 3, 4, 5, 6, 7);

    // PV: B-frag lane holds V[kv = g*8+j][d = dt*16 + c] = Vt[d][t0 + g*8 + j]
#pragma unroll
    for (int dt = 0; dt < 4; ++dt) {
      f16x8 vb = *(const f16x8*)(vbase + (size_t)(dt * 16 + c) * NKV + t0 + g * 8);
      o[dt] = __builtin_amdgcn_mfma_f32_16x16x32_f16(pa, vb, o[dt], 0, 0, 0);
    }
  }

  // epilogue: lane holds O[q = g*4+r][d = dt*16+c]
  float inv[4];
#pragma unroll
  for (int r = 0; r < 4; ++r) inv[r] = 1.0f / lsum[r];
  float* obase = op + ((size_t)b * NQ + qt * 64 + wave * 16) * 384 + h * 64;
#pragma unroll
  for (int dt = 0; dt < 4; ++dt)
#pragma unroll
    for (int r = 0; r < 4; ++r)
      obase[(size_t)(g * 4 + r) * 384 + dt * 16 + c] = o[dt][r] * inv[r];
}

extern "C" void kernel_launch(void* const* d_in, const int* in_sizes, int n_in,
                              void* d_out, int out_size, void* d_ws, size_t ws_size,
                              hipStream_t stream) {
  const float* inputs_q  = (const float*)d_in[0];
  const float* inputs_kv = (const float*)d_in[1];
  const float* out_kern  = (const float*)d_in[2];
  const float* q_dwk = (const float*)d_in[3];
  const float* q_bs  = (const float*)d_in[4];
  const float* q_bb  = (const float*)d_in[5];
  const float* q_bm  = (const float*)d_in[6];
  const float* q_bv  = (const float*)d_in[7];
  const float* q_pwk = (const float*)d_in[8];
  const float* k_dwk = (const float*)d_in[9];
  const float* k_bs  = (const float*)d_in[10];
  const float* k_bb  = (const float*)d_in[11];
  const float* k_bm  = (const float*)d_in[12];
  const float* k_bv  = (const float*)d_in[13];
  const float* k_pwk = (const float*)d_in[14];
  const float* v_dwk = (const float*)d_in[15];
  const float* v_bs  = (const float*)d_in[16];
  const float* v_bb  = (const float*)d_in[17];
  const float* v_bm  = (const float*)d_in[18];
  const float* v_bv  = (const float*)d_in[19];
  const float* v_pwk = (const float*)d_in[20];

  float* ws = (float*)d_ws;
  // workspace layout (float units)
  const size_t Q_DWBN = 0;            // 25088*384 f32 (aliased by O after q pw GEMM)
  const size_t K_DWBN = 9633792;      // 6272*384 f32
  const size_t V_DWBN = 12042240;     // 6272*384 f32
  const size_t QF16   = 14450688;     // 25088*384 f16 = 4816896 f32
  const size_t KF16   = 19267584;     // 6272*384 f16 = 1204224 f32
  const size_t VF16   = 20471808;     // 6272*384 f16
  const size_t VT     = 21676032;     // 8*384*784 f16 (+slack)
  const size_t O_BUF  = 0;

  f16* qf16 = (f16*)(ws + QF16);
  f16* kf16 = (f16*)(ws + KF16);
  f16* vf16 = (f16*)(ws + VF16);
  f16* vtp  = (f16*)(ws + VT);

  // 1. depthwise + BN
  dw_bn_s1<<<9408, 256, 0, stream>>>(inputs_q, q_dwk, q_bs, q_bb, q_bm, q_bv, ws + Q_DWBN);
  dw_bn_s2_kv<<<2352, 256, 0, stream>>>(inputs_kv,
      k_dwk, k_bs, k_bb, k_bm, k_bv,
      v_dwk, v_bs, v_bb, v_bm, v_bv,
      ws + K_DWBN, ws + V_DWBN);
  // 2. pointwise GEMMs -> f16 (q folded with 1/8)
  gemm384<1><<<dim3(392, 6), 256, 0, stream>>>(ws + Q_DWBN, q_pwk, nullptr, qf16, 0.125f);
  gemm384<1><<<dim3(98, 6), 256, 0, stream>>>(ws + K_DWBN, k_pwk, nullptr, kf16, 1.0f);
  gemm384<1><<<dim3(98, 6), 256, 0, stream>>>(ws + V_DWBN, v_pwk, nullptr, vf16, 1.0f);
  // 3. V transpose per batch: [b*784+kv][384] -> [b*384+c][784]
  transpose_f16<<<dim3(25, 12, 8), 256, 0, stream>>>(vf16, vtp);
  // 4. MFMA attention
  attn_mfma<<<BB * NHD * 49, 256, 0, stream>>>(qf16, kf16, vtp, ws + O_BUF);
  // 5. output projection (fp32)
  gemm384<0><<<dim3(392, 6), 256, 0, stream>>>(ws + O_BUF, out_kern, (float*)d_out, nullptr, 1.0f);
}

// Round 3
// 258.736 us; speedup vs baseline: 3.9249x; 1.8373x over previous
//
#include <hip/hip_runtime.h>
#include <hip/hip_bf16.h>
#include <hip/hip_fp16.h>

// Problem constants
#define BB 8
#define HH 56
#define WW 56
#define CC 384
#define NHD 6
#define DD 64
#define HK 28
#define WK 28
#define NQ (HH*WW)       // 3136
#define NKV (HK*WK)      // 784
#define NTOK (BB*NQ)     // 25088
#define NTOKKV (BB*NKV)  // 6272
#define BN_EPS 1e-5f

typedef _Float16 f16;
typedef _Float16 f16x4 __attribute__((ext_vector_type(4)));
typedef _Float16 f16x8 __attribute__((ext_vector_type(8)));
typedef float f32x4 __attribute__((ext_vector_type(4)));

// ---------------- depthwise conv + BN, stride 1 (q path), f16 out ----------------
__global__ __launch_bounds__(256) void dw_bn_s1(
    const float* __restrict__ in, const float* __restrict__ w,
    const float* __restrict__ bns, const float* __restrict__ bnb,
    const float* __restrict__ bnm, const float* __restrict__ bnv,
    f16* __restrict__ out) {
  int idx = blockIdx.x * 256 + threadIdx.x;      // < NTOK*96
  int pix = idx / 96;
  int c = (idx % 96) * 4;
  int b = pix / (HH * WW);
  int p = pix % (HH * WW);
  int y = p / WW, x = p % WW;
  float ax = 0.f, ay = 0.f, az = 0.f, aw = 0.f;
#pragma unroll
  for (int kh = 0; kh < 3; ++kh) {
    int iy = y + kh - 1;
    if ((unsigned)iy >= (unsigned)HH) continue;
#pragma unroll
    for (int kw = 0; kw < 3; ++kw) {
      int ix = x + kw - 1;
      if ((unsigned)ix >= (unsigned)WW) continue;
      const float4 v = *(const float4*)(in + (((size_t)(b * HH + iy) * WW + ix) * CC + c));
      const float4 wk = *(const float4*)(w + ((kh * 3 + kw) * CC + c));
      ax = fmaf(v.x, wk.x, ax); ay = fmaf(v.y, wk.y, ay);
      az = fmaf(v.z, wk.z, az); aw = fmaf(v.w, wk.w, aw);
    }
  }
  const float4 s = *(const float4*)(bns + c);
  const float4 bi = *(const float4*)(bnb + c);
  const float4 m = *(const float4*)(bnm + c);
  const float4 va = *(const float4*)(bnv + c);
  f16x4 r;
  float g;
  g = s.x * rsqrtf(va.x + BN_EPS); r[0] = (f16)fmaf(ax - m.x, g, bi.x);
  g = s.y * rsqrtf(va.y + BN_EPS); r[1] = (f16)fmaf(ay - m.y, g, bi.y);
  g = s.z * rsqrtf(va.z + BN_EPS); r[2] = (f16)fmaf(az - m.z, g, bi.z);
  g = s.w * rsqrtf(va.w + BN_EPS); r[3] = (f16)fmaf(aw - m.w, g, bi.w);
  *(f16x4*)(out + (size_t)pix * CC + c) = r;
}

// -------- fused depthwise conv + BN, stride 2, k and v from same input, f16 out --------
__global__ __launch_bounds__(256) void dw_bn_s2_kv(
    const float* __restrict__ in,
    const float* __restrict__ wk_, const float* __restrict__ kbs, const float* __restrict__ kbb,
    const float* __restrict__ kbm, const float* __restrict__ kbv,
    const float* __restrict__ wv_, const float* __restrict__ vbs, const float* __restrict__ vbb,
    const float* __restrict__ vbm, const float* __restrict__ vbv,
    f16* __restrict__ outk, f16* __restrict__ outv) {
  int idx = blockIdx.x * 256 + threadIdx.x;      // < NTOKKV*96
  int pix = idx / 96;
  int c = (idx % 96) * 4;
  int b = pix / (HK * WK);
  int p = pix % (HK * WK);
  int oy = p / WK, ox = p % WK;
  float kx = 0, ky = 0, kz = 0, kw4 = 0;
  float vx = 0, vy = 0, vz = 0, vw4 = 0;
#pragma unroll
  for (int kh = 0; kh < 3; ++kh) {
    int iy = oy * 2 + kh;
    if (iy >= HH) continue;
#pragma unroll
    for (int kwi = 0; kwi < 3; ++kwi) {
      int ix = ox * 2 + kwi;
      if (ix >= WW) continue;
      const float4 v = *(const float4*)(in + (((size_t)(b * HH + iy) * WW + ix) * CC + c));
      const float4 a = *(const float4*)(wk_ + ((kh * 3 + kwi) * CC + c));
      const float4 bq = *(const float4*)(wv_ + ((kh * 3 + kwi) * CC + c));
      kx = fmaf(v.x, a.x, kx); ky = fmaf(v.y, a.y, ky);
      kz = fmaf(v.z, a.z, kz); kw4 = fmaf(v.w, a.w, kw4);
      vx = fmaf(v.x, bq.x, vx); vy = fmaf(v.y, bq.y, vy);
      vz = fmaf(v.z, bq.z, vz); vw4 = fmaf(v.w, bq.w, vw4);
    }
  }
  {
    const float4 s = *(const float4*)(kbs + c);
    const float4 bi = *(const float4*)(kbb + c);
    const float4 m = *(const float4*)(kbm + c);
    const float4 va = *(const float4*)(kbv + c);
    f16x4 r; float g;
    g = s.x * rsqrtf(va.x + BN_EPS); r[0] = (f16)fmaf(kx - m.x, g, bi.x);
    g = s.y * rsqrtf(va.y + BN_EPS); r[1] = (f16)fmaf(ky - m.y, g, bi.y);
    g = s.z * rsqrtf(va.z + BN_EPS); r[2] = (f16)fmaf(kz - m.z, g, bi.z);
    g = s.w * rsqrtf(va.w + BN_EPS); r[3] = (f16)fmaf(kw4 - m.w, g, bi.w);
    *(f16x4*)(outk + (size_t)pix * CC + c) = r;
  }
  {
    const float4 s = *(const float4*)(vbs + c);
    const float4 bi = *(const float4*)(vbb + c);
    const float4 m = *(const float4*)(vbm + c);
    const float4 va = *(const float4*)(vbv + c);
    f16x4 r; float g;
    g = s.x * rsqrtf(va.x + BN_EPS); r[0] = (f16)fmaf(vx - m.x, g, bi.x);
    g = s.y * rsqrtf(va.y + BN_EPS); r[1] = (f16)fmaf(vy - m.y, g, bi.y);
    g = s.z * rsqrtf(va.z + BN_EPS); r[2] = (f16)fmaf(vz - m.z, g, bi.z);
    g = s.w * rsqrtf(va.w + BN_EPS); r[3] = (f16)fmaf(vw4 - m.w, g, bi.w);
    *(f16x4*)(outv + (size_t)pix * CC + c) = r;
  }
}

// ---- transpose-convert 4 weight matrices: fp32 [384(k)][384(n)] -> f16 [n][k] ----
__global__ __launch_bounds__(256) void convert_w(
    const float* __restrict__ w0, const float* __restrict__ w1,
    const float* __restrict__ w2, const float* __restrict__ w3,
    f16* __restrict__ o0, f16* __restrict__ o1,
    f16* __restrict__ o2, f16* __restrict__ o3) {
  const float* src = blockIdx.z == 0 ? w0 : blockIdx.z == 1 ? w1 : blockIdx.z == 2 ? w2 : w3;
  f16* dst = blockIdx.z == 0 ? o0 : blockIdx.z == 1 ? o1 : blockIdx.z == 2 ? o2 : o3;
  __shared__ float t[32][33];
  const int k0 = blockIdx.x * 32, n0 = blockIdx.y * 32;
  const int x = threadIdx.x & 31, y = threadIdx.x >> 5;
#pragma unroll
  for (int i = 0; i < 4; ++i) t[y + i * 8][x] = src[(size_t)(k0 + y + i * 8) * 384 + n0 + x];
  __syncthreads();
#pragma unroll
  for (int i = 0; i < 4; ++i)
    dst[(size_t)(n0 + y + i * 8) * 384 + k0 + x] = (f16)t[x][y + i * 8];
}

// ------------- f16 MFMA GEMM: C[M,384] = scale * A[M,384] @ Bt^T -------------
// A row-major f16, Bt [n][k] f16 (pre-transposed). Tile 128x64, 4 waves (2x2),
// each wave 64x32 = 4x2 fragments of 16x16x32. OF16: f16 out, else fp32 out.
template <int OF16>
__global__ __launch_bounds__(256) void gemm_mfma(
    const f16* __restrict__ A, const f16* __restrict__ Bt,
    float* __restrict__ Cf, f16* __restrict__ Ch, float scale) {
  __shared__ f16 As[128 * 32];   // [row][k], 64 B per row
  __shared__ f16 Bs[64 * 32];    // [col][k], 64 B per col
  const int tid = threadIdx.x;
  const int wave = tid >> 6, lane = tid & 63;
  const int c = lane & 15, g = lane >> 4;
  const int wr = wave >> 1, wc = wave & 1;
  const int row0 = blockIdx.x * 128, col0 = blockIdx.y * 64;

  f32x4 acc[4][2] = {};

  for (int k0 = 0; k0 < 384; k0 += 32) {
    __syncthreads();    // LDS reads of previous step done
    {
      // stage A: chunk i (16B) = row*4 + c4; two calls per thread
      int i0 = wave * 64 + lane;
      const f16* s0 = A + (size_t)(row0 + (i0 >> 2)) * 384 + k0 + (i0 & 3) * 8;
      __builtin_amdgcn_global_load_lds(
          (const __attribute__((address_space(1))) void*)s0,
          (__attribute__((address_space(3))) void*)(As + wave * 512), 16, 0, 0);
      int i1 = 256 + wave * 64 + lane;
      const f16* s1 = A + (size_t)(row0 + (i1 >> 2)) * 384 + k0 + (i1 & 3) * 8;
      __builtin_amdgcn_global_load_lds(
          (const __attribute__((address_space(1))) void*)s1,
          (__attribute__((address_space(3))) void*)(As + 2048 + wave * 512), 16, 0, 0);
      // stage B: chunk i = col*4 + c4
      int ib = wave * 64 + lane;
      const f16* sb = Bt + (size_t)(col0 + (ib >> 2)) * 384 + k0 + (ib & 3) * 8;
      __builtin_amdgcn_global_load_lds(
          (const __attribute__((address_space(1))) void*)sb,
          (__attribute__((address_space(3))) void*)(Bs + wave * 512), 16, 0, 0);
    }
    __syncthreads();    // staging complete (vmcnt drained by barrier)

    f16x8 bfr[2];
#pragma unroll
    for (int n = 0; n < 2; ++n)
      bfr[n] = *(const f16x8*)(Bs + (size_t)(wc * 32 + n * 16 + c) * 32 + g * 8);
#pragma unroll
    for (int m = 0; m < 4; ++m) {
      f16x8 af = *(const f16x8*)(As + (size_t)(wr * 64 + m * 16 + c) * 32 + g * 8);
      acc[m][0] = __builtin_amdgcn_mfma_f32_16x16x32_f16(af, bfr[0], acc[m][0], 0, 0, 0);
      acc[m][1] = __builtin_amdgcn_mfma_f32_16x16x32_f16(af, bfr[1], acc[m][1], 0, 0, 0);
    }
  }

  // epilogue: lane holds C[row0+wr*64+m*16+g*4+r][col0+wc*32+n*16+c]
#pragma unroll
  for (int m = 0; m < 4; ++m)
#pragma unroll
    for (int n = 0; n < 2; ++n)
#pragma unroll
      for (int r = 0; r < 4; ++r) {
        const size_t row = row0 + wr * 64 + m * 16 + g * 4 + r;
        const size_t col = col0 + wc * 32 + n * 16 + c;
        if (OF16) Ch[row * 384 + col] = (f16)(acc[m][n][r] * scale);
        else      Cf[row * 384 + col] = acc[m][n][r] * scale;
      }
}

// ------------- per-batch transpose: in [b*784+kv][384] -> out [b*384+c][784] -------------
__global__ __launch_bounds__(256) void transpose_f16(
    const f16* __restrict__ in, f16* __restrict__ out) {
  __shared__ f16 t[32][33];
  const int b = blockIdx.z;
  const int kv0 = blockIdx.x * 32, c0 = blockIdx.y * 32;
  const int x = threadIdx.x & 31, y = threadIdx.x >> 5;  // 32 x 8
#pragma unroll
  for (int i = 0; i < 4; ++i) {
    int row = y + i * 8;
    int kv = kv0 + row;
    if (kv < NKV) t[row][x] = in[((size_t)b * NKV + kv) * 384 + c0 + x];
  }
  __syncthreads();
#pragma unroll
  for (int i = 0; i < 4; ++i) {
    int row = y + i * 8;
    if (kv0 + x < NKV)
      out[((size_t)b * 384 + c0 + row) * NKV + kv0 + x] = t[x][row];
  }
}

// ------------- f16 MFMA flash attention -------------
// grid = B*NH*(3136/64); block = 256 (4 waves x 16 q-rows). O out in f16.
#define KVT 32
__global__ __launch_bounds__(256) void attn_mfma(
    const f16* __restrict__ qp, const f16* __restrict__ kp,
    const f16* __restrict__ vt, f16* __restrict__ op) {
  __shared__ f16 Ks[KVT * 64];            // chunk-swizzled: row kv, chunk j stored at j^(kv&7)
  __shared__ f16 Ps[4][16 * 36];          // per-wave P, row stride 36 halves
  const int bid = blockIdx.x;
  const int qt = bid % 49;
  const int bh = bid / 49;
  const int h = bh % NHD, b = bh / NHD;
  const int tid = threadIdx.x;
  const int wave = tid >> 6, lane = tid & 63;
  const int c = lane & 15, g = lane >> 4;

  const size_t qrow = (size_t)b * NQ + qt * 64 + wave * 16 + c;
  f16x8 qa0 = *(const f16x8*)(qp + qrow * 384 + h * 64 + g * 8);
  f16x8 qa1 = *(const f16x8*)(qp + qrow * 384 + h * 64 + 32 + g * 8);

  const int st_kv = tid >> 3;
  const int st_l = (tid & 7) ^ (st_kv & 7);

  f32x4 o[4] = {};
  float mrun[4], lsum[4];
#pragma unroll
  for (int r = 0; r < 4; ++r) { mrun[r] = -1e30f; lsum[r] = 0.f; }

  const f16* vbase = vt + ((size_t)b * 384 + h * 64) * NKV;
  f16* pw = &Ps[wave][0];

  for (int t0 = 0; t0 < NKV; t0 += KVT) {
    __syncthreads();
    {
      int kv = t0 + st_kv;
      if (kv > NKV - 1) kv = NKV - 1;
      const f16* gsrc = kp + ((size_t)b * NKV + kv) * 384 + h * 64 + st_l * 8;
      __builtin_amdgcn_global_load_lds(
          (const __attribute__((address_space(1))) void*)gsrc,
          (__attribute__((address_space(3))) void*)(Ks + wave * 512),
          16, 0, 0);
    }
    __syncthreads();

    f32x4 s0 = {0.f, 0.f, 0.f, 0.f}, s1 = {0.f, 0.f, 0.f, 0.f};
#pragma unroll
    for (int kh = 0; kh < 2; ++kh) {
      const f16x8 qa = kh ? qa1 : qa0;
      {
        int row = c;
        int ch = (kh * 4 + g) ^ (row & 7);
        f16x8 kb = *(const f16x8*)(Ks + row * 64 + ch * 8);
        s0 = __builtin_amdgcn_mfma_f32_16x16x32_f16(qa, kb, s0, 0, 0, 0);
      }
      {
        int row = 16 + c;
        int ch = (kh * 4 + g) ^ (row & 7);
        f16x8 kb = *(const f16x8*)(Ks + row * 64 + ch * 8);
        s1 = __builtin_amdgcn_mfma_f32_16x16x32_f16(qa, kb, s1, 0, 0, 0);
      }
    }
    if (t0 + KVT > NKV) {
#pragma unroll
      for (int r = 0; r < 4; ++r) {
        if (t0 + c >= NKV) s0[r] = -1e30f;
        if (t0 + 16 + c >= NKV) s1[r] = -1e30f;
      }
    }

    float corr[4];
#pragma unroll
    for (int r = 0; r < 4; ++r) {
      float mt = fmaxf(s0[r], s1[r]);
      mt = fmaxf(mt, __shfl_xor(mt, 1));
      mt = fmaxf(mt, __shfl_xor(mt, 2));
      mt = fmaxf(mt, __shfl_xor(mt, 4));
      mt = fmaxf(mt, __shfl_xor(mt, 8));
      const float mnew = fmaxf(mrun[r], mt);
      corr[r] = __expf(mrun[r] - mnew);
      mrun[r] = mnew;
      const float p0 = __expf(s0[r] - mnew);
      const float p1 = __expf(s1[r] - mnew);
      s0[r] = p0; s1[r] = p1;
      float ps = p0 + p1;
      ps += __shfl_xor(ps, 1);
      ps += __shfl_xor(ps, 2);
      ps += __shfl_xor(ps, 4);
      ps += __shfl_xor(ps, 8);
      lsum[r] = lsum[r] * corr[r] + ps;
    }
#pragma unroll
    for (int dt = 0; dt < 4; ++dt)
#pragma unroll
      for (int r = 0; r < 4; ++r) o[dt][r] *= corr[r];

#pragma unroll
    for (int r = 0; r < 4; ++r) {
      const int row = g * 4 + r;
      pw[row * 36 + c] = (f16)s0[r];
      pw[row * 36 + 16 + c] = (f16)s1[r];
    }
    f16x4 plo = *(const f16x4*)(pw + c * 36 + g * 8);
    f16x4 phi = *(const f16x4*)(pw + c * 36 + g * 8 + 4);
    f16x8 pa = __builtin_shufflevector(plo, phi, 0, 1, 2, 3, 4, 5, 6, 7);

#pragma unroll
    for (int dt = 0; dt < 4; ++dt) {
      f16x8 vb = *(const f16x8*)(vbase + (size_t)(dt * 16 + c) * NKV + t0 + g * 8);
      o[dt] = __builtin_amdgcn_mfma_f32_16x16x32_f16(pa, vb, o[dt], 0, 0, 0);
    }
  }

  float inv[4];
#pragma unroll
  for (int r = 0; r < 4; ++r) inv[r] = 1.0f / lsum[r];
  f16* obase = op + ((size_t)b * NQ + qt * 64 + wave * 16) * 384 + h * 64;
#pragma unroll
  for (int dt = 0; dt < 4; ++dt)
#pragma unroll
    for (int r = 0; r < 4; ++r)
      obase[(size_t)(g * 4 + r) * 384 + dt * 16 + c] = (f16)(o[dt][r] * inv[r]);
}

extern "C" void kernel_launch(void* const* d_in, const int* in_sizes, int n_in,
                              void* d_out, int out_size, void* d_ws, size_t ws_size,
                              hipStream_t stream) {
  const float* inputs_q  = (const float*)d_in[0];
  const float* inputs_kv = (const float*)d_in[1];
  const float* out_kern  = (const float*)d_in[2];
  const float* q_dwk = (const float*)d_in[3];
  const float* q_bs  = (const float*)d_in[4];
  const float* q_bb  = (const float*)d_in[5];
  const float* q_bm  = (const float*)d_in[6];
  const float* q_bv  = (const float*)d_in[7];
  const float* q_pwk = (const float*)d_in[8];
  const float* k_dwk = (const float*)d_in[9];
  const float* k_bs  = (const float*)d_in[10];
  const float* k_bb  = (const float*)d_in[11];
  const float* k_bm  = (const float*)d_in[12];
  const float* k_bv  = (const float*)d_in[13];
  const float* k_pwk = (const float*)d_in[14];
  const float* v_dwk = (const float*)d_in[15];
  const float* v_bs  = (const float*)d_in[16];
  const float* v_bb  = (const float*)d_in[17];
  const float* v_bm  = (const float*)d_in[18];
  const float* v_bv  = (const float*)d_in[19];
  const float* v_pwk = (const float*)d_in[20];

  char* wsb = (char*)d_ws;
  // byte offsets
  f16* qdw = (f16*)(wsb + 0);             // 25088*384 f16
  f16* kdw = (f16*)(wsb + 19267584);      // 6272*384 f16
  f16* vdw = (f16*)(wsb + 24084480);      // 6272*384 f16
  f16* qf  = (f16*)(wsb + 28901376);      // 25088*384 f16
  f16* kf  = (f16*)(wsb + 48168960);      // 6272*384 f16
  f16* vf  = (f16*)(wsb + 52985856);      // 6272*384 f16
  f16* vtp = (f16*)(wsb + 57802752);      // 8*384*784 f16
  f16* of  = (f16*)(wsb + 62619648);      // 25088*384 f16
  f16* wqt = (f16*)(wsb + 81887232);      // 384*384 f16 x4
  f16* wkt = (f16*)(wsb + 82182144);
  f16* wvt = (f16*)(wsb + 82477056);
  f16* wot = (f16*)(wsb + 82771968);

  // 0. weight transpose-convert (fp32 [k][n] -> f16 [n][k])
  convert_w<<<dim3(12, 12, 4), 256, 0, stream>>>(
      q_pwk, k_pwk, v_pwk, out_kern, wqt, wkt, wvt, wot);
  // 1. depthwise + BN -> f16
  dw_bn_s1<<<9408, 256, 0, stream>>>(inputs_q, q_dwk, q_bs, q_bb, q_bm, q_bv, qdw);
  dw_bn_s2_kv<<<2352, 256, 0, stream>>>(inputs_kv,
      k_dwk, k_bs, k_bb, k_bm, k_bv,
      v_dwk, v_bs, v_bb, v_bm, v_bv,
      kdw, vdw);
  // 2. pointwise GEMMs (MFMA, f16 out; q folded with 1/8)
  gemm_mfma<1><<<dim3(196, 6), 256, 0, stream>>>(qdw, wqt, nullptr, qf, 0.125f);
  gemm_mfma<1><<<dim3(49, 6), 256, 0, stream>>>(kdw, wkt, nullptr, kf, 1.0f);
  gemm_mfma<1><<<dim3(49, 6), 256, 0, stream>>>(vdw, wvt, nullptr, vf, 1.0f);
  // 3. V transpose per batch
  transpose_f16<<<dim3(25, 12, 8), 256, 0, stream>>>(vf, vtp);
  // 4. MFMA attention -> f16 O
  attn_mfma<<<BB * NHD * 49, 256, 0, stream>>>(qf, kf, vtp, of);
  // 5. output projection (MFMA, fp32 out)
  gemm_mfma<0><<<dim3(196, 6), 256, 0, stream>>>(of, wot, (float*)d_out, nullptr, 1.0f);
}

// Round 4
// 196.927 us; speedup vs baseline: 5.1568x; 1.3139x over previous
//
#include <hip/hip_runtime.h>
#include <hip/hip_bf16.h>
#include <hip/hip_fp16.h>

// Problem constants
#define BB 8
#define HH 56
#define WW 56
#define CC 384
#define NHD 6
#define DD 64
#define HK 28
#define WK 28
#define NQ (HH*WW)       // 3136
#define NKV (HK*WK)      // 784
#define NTOK (BB*NQ)     // 25088
#define NTOKKV (BB*NKV)  // 6272
#define BN_EPS 1e-5f
#define LOG2E 1.44269504f

typedef _Float16 f16;
typedef _Float16 f16x4 __attribute__((ext_vector_type(4)));
typedef _Float16 f16x8 __attribute__((ext_vector_type(8)));
typedef float f32x4 __attribute__((ext_vector_type(4)));

// ---------------- depthwise conv + BN, stride 1 (q path), f16 out ----------------
__global__ __launch_bounds__(256) void dw_bn_s1(
    const float* __restrict__ in, const float* __restrict__ w,
    const float* __restrict__ bns, const float* __restrict__ bnb,
    const float* __restrict__ bnm, const float* __restrict__ bnv,
    f16* __restrict__ out) {
  int idx = blockIdx.x * 256 + threadIdx.x;      // < NTOK*96
  int pix = idx / 96;
  int c = (idx % 96) * 4;
  int b = pix / (HH * WW);
  int p = pix % (HH * WW);
  int y = p / WW, x = p % WW;
  float ax = 0.f, ay = 0.f, az = 0.f, aw = 0.f;
#pragma unroll
  for (int kh = 0; kh < 3; ++kh) {
    int iy = y + kh - 1;
    if ((unsigned)iy >= (unsigned)HH) continue;
#pragma unroll
    for (int kw = 0; kw < 3; ++kw) {
      int ix = x + kw - 1;
      if ((unsigned)ix >= (unsigned)WW) continue;
      const float4 v = *(const float4*)(in + (((size_t)(b * HH + iy) * WW + ix) * CC + c));
      const float4 wk = *(const float4*)(w + ((kh * 3 + kw) * CC + c));
      ax = fmaf(v.x, wk.x, ax); ay = fmaf(v.y, wk.y, ay);
      az = fmaf(v.z, wk.z, az); aw = fmaf(v.w, wk.w, aw);
    }
  }
  const float4 s = *(const float4*)(bns + c);
  const float4 bi = *(const float4*)(bnb + c);
  const float4 m = *(const float4*)(bnm + c);
  const float4 va = *(const float4*)(bnv + c);
  f16x4 r;
  float g;
  g = s.x * rsqrtf(va.x + BN_EPS); r[0] = (f16)fmaf(ax - m.x, g, bi.x);
  g = s.y * rsqrtf(va.y + BN_EPS); r[1] = (f16)fmaf(ay - m.y, g, bi.y);
  g = s.z * rsqrtf(va.z + BN_EPS); r[2] = (f16)fmaf(az - m.z, g, bi.z);
  g = s.w * rsqrtf(va.w + BN_EPS); r[3] = (f16)fmaf(aw - m.w, g, bi.w);
  *(f16x4*)(out + (size_t)pix * CC + c) = r;
}

// -------- fused depthwise conv + BN, stride 2, k and v from same input, f16 out --------
__global__ __launch_bounds__(256) void dw_bn_s2_kv(
    const float* __restrict__ in,
    const float* __restrict__ wk_, const float* __restrict__ kbs, const float* __restrict__ kbb,
    const float* __restrict__ kbm, const float* __restrict__ kbv,
    const float* __restrict__ wv_, const float* __restrict__ vbs, const float* __restrict__ vbb,
    const float* __restrict__ vbm, const float* __restrict__ vbv,
    f16* __restrict__ outk, f16* __restrict__ outv) {
  int idx = blockIdx.x * 256 + threadIdx.x;      // < NTOKKV*96
  int pix = idx / 96;
  int c = (idx % 96) * 4;
  int b = pix / (HK * WK);
  int p = pix % (HK * WK);
  int oy = p / WK, ox = p % WK;
  float kx = 0, ky = 0, kz = 0, kw4 = 0;
  float vx = 0, vy = 0, vz = 0, vw4 = 0;
#pragma unroll
  for (int kh = 0; kh < 3; ++kh) {
    int iy = oy * 2 + kh;
    if (iy >= HH) continue;
#pragma unroll
    for (int kwi = 0; kwi < 3; ++kwi) {
      int ix = ox * 2 + kwi;
      if (ix >= WW) continue;
      const float4 v = *(const float4*)(in + (((size_t)(b * HH + iy) * WW + ix) * CC + c));
      const float4 a = *(const float4*)(wk_ + ((kh * 3 + kwi) * CC + c));
      const float4 bq = *(const float4*)(wv_ + ((kh * 3 + kwi) * CC + c));
      kx = fmaf(v.x, a.x, kx); ky = fmaf(v.y, a.y, ky);
      kz = fmaf(v.z, a.z, kz); kw4 = fmaf(v.w, a.w, kw4);
      vx = fmaf(v.x, bq.x, vx); vy = fmaf(v.y, bq.y, vy);
      vz = fmaf(v.z, bq.z, vz); vw4 = fmaf(v.w, bq.w, vw4);
    }
  }
  {
    const float4 s = *(const float4*)(kbs + c);
    const float4 bi = *(const float4*)(kbb + c);
    const float4 m = *(const float4*)(kbm + c);
    const float4 va = *(const float4*)(kbv + c);
    f16x4 r; float g;
    g = s.x * rsqrtf(va.x + BN_EPS); r[0] = (f16)fmaf(kx - m.x, g, bi.x);
    g = s.y * rsqrtf(va.y + BN_EPS); r[1] = (f16)fmaf(ky - m.y, g, bi.y);
    g = s.z * rsqrtf(va.z + BN_EPS); r[2] = (f16)fmaf(kz - m.z, g, bi.z);
    g = s.w * rsqrtf(va.w + BN_EPS); r[3] = (f16)fmaf(kw4 - m.w, g, bi.w);
    *(f16x4*)(outk + (size_t)pix * CC + c) = r;
  }
  {
    const float4 s = *(const float4*)(vbs + c);
    const float4 bi = *(const float4*)(vbb + c);
    const float4 m = *(const float4*)(vbm + c);
    const float4 va = *(const float4*)(vbv + c);
    f16x4 r; float g;
    g = s.x * rsqrtf(va.x + BN_EPS); r[0] = (f16)fmaf(vx - m.x, g, bi.x);
    g = s.y * rsqrtf(va.y + BN_EPS); r[1] = (f16)fmaf(vy - m.y, g, bi.y);
    g = s.z * rsqrtf(va.z + BN_EPS); r[2] = (f16)fmaf(vz - m.z, g, bi.z);
    g = s.w * rsqrtf(va.w + BN_EPS); r[3] = (f16)fmaf(vw4 - m.w, g, bi.w);
    *(f16x4*)(outv + (size_t)pix * CC + c) = r;
  }
}

// ---- transpose-convert 4 weight matrices: fp32 [384(k)][384(n)] -> f16 [n][k] ----
__global__ __launch_bounds__(256) void convert_w(
    const float* __restrict__ w0, const float* __restrict__ w1,
    const float* __restrict__ w2, const float* __restrict__ w3,
    f16* __restrict__ o0, f16* __restrict__ o1,
    f16* __restrict__ o2, f16* __restrict__ o3) {
  const float* src = blockIdx.z == 0 ? w0 : blockIdx.z == 1 ? w1 : blockIdx.z == 2 ? w2 : w3;
  f16* dst = blockIdx.z == 0 ? o0 : blockIdx.z == 1 ? o1 : blockIdx.z == 2 ? o2 : o3;
  __shared__ float t[32][33];
  const int k0 = blockIdx.x * 32, n0 = blockIdx.y * 32;
  const int x = threadIdx.x & 31, y = threadIdx.x >> 5;
#pragma unroll
  for (int i = 0; i < 4; ++i) t[y + i * 8][x] = src[(size_t)(k0 + y + i * 8) * 384 + n0 + x];
  __syncthreads();
#pragma unroll
  for (int i = 0; i < 4; ++i)
    dst[(size_t)(n0 + y + i * 8) * 384 + k0 + x] = (f16)t[x][y + i * 8];
}

// ------------- f16 MFMA GEMM: C[M,384] = scale * A[M,384] @ Bt^T -------------
template <int OF16>
__global__ __launch_bounds__(256) void gemm_mfma(
    const f16* __restrict__ A, const f16* __restrict__ Bt,
    float* __restrict__ Cf, f16* __restrict__ Ch, float scale) {
  __shared__ f16 As[128 * 32];   // [row][k], 64 B per row
  __shared__ f16 Bs[64 * 32];    // [col][k], 64 B per col
  const int tid = threadIdx.x;
  const int wave = tid >> 6, lane = tid & 63;
  const int c = lane & 15, g = lane >> 4;
  const int wr = wave >> 1, wc = wave & 1;
  const int row0 = blockIdx.x * 128, col0 = blockIdx.y * 64;

  f32x4 acc[4][2] = {};

  for (int k0 = 0; k0 < 384; k0 += 32) {
    __syncthreads();
    {
      int i0 = wave * 64 + lane;
      const f16* s0 = A + (size_t)(row0 + (i0 >> 2)) * 384 + k0 + (i0 & 3) * 8;
      __builtin_amdgcn_global_load_lds(
          (const __attribute__((address_space(1))) void*)s0,
          (__attribute__((address_space(3))) void*)(As + wave * 512), 16, 0, 0);
      int i1 = 256 + wave * 64 + lane;
      const f16* s1 = A + (size_t)(row0 + (i1 >> 2)) * 384 + k0 + (i1 & 3) * 8;
      __builtin_amdgcn_global_load_lds(
          (const __attribute__((address_space(1))) void*)s1,
          (__attribute__((address_space(3))) void*)(As + 2048 + wave * 512), 16, 0, 0);
      int ib = wave * 64 + lane;
      const f16* sb = Bt + (size_t)(col0 + (ib >> 2)) * 384 + k0 + (ib & 3) * 8;
      __builtin_amdgcn_global_load_lds(
          (const __attribute__((address_space(1))) void*)sb,
          (__attribute__((address_space(3))) void*)(Bs + wave * 512), 16, 0, 0);
    }
    __syncthreads();

    f16x8 bfr[2];
#pragma unroll
    for (int n = 0; n < 2; ++n)
      bfr[n] = *(const f16x8*)(Bs + (size_t)(wc * 32 + n * 16 + c) * 32 + g * 8);
#pragma unroll
    for (int m = 0; m < 4; ++m) {
      f16x8 af = *(const f16x8*)(As + (size_t)(wr * 64 + m * 16 + c) * 32 + g * 8);
      acc[m][0] = __builtin_amdgcn_mfma_f32_16x16x32_f16(af, bfr[0], acc[m][0], 0, 0, 0);
      acc[m][1] = __builtin_amdgcn_mfma_f32_16x16x32_f16(af, bfr[1], acc[m][1], 0, 0, 0);
    }
  }

#pragma unroll
  for (int m = 0; m < 4; ++m)
#pragma unroll
    for (int n = 0; n < 2; ++n)
#pragma unroll
      for (int r = 0; r < 4; ++r) {
        const size_t row = row0 + wr * 64 + m * 16 + g * 4 + r;
        const size_t col = col0 + wc * 32 + n * 16 + c;
        if (OF16) Ch[row * 384 + col] = (f16)(acc[m][n][r] * scale);
        else      Cf[row * 384 + col] = acc[m][n][r] * scale;
      }
}

// ------------- per-batch transpose: in [b*784+kv][384] -> out [b*384+c][784] -------------
__global__ __launch_bounds__(256) void transpose_f16(
    const f16* __restrict__ in, f16* __restrict__ out) {
  __shared__ f16 t[32][33];
  const int b = blockIdx.z;
  const int kv0 = blockIdx.x * 32, c0 = blockIdx.y * 32;
  const int x = threadIdx.x & 31, y = threadIdx.x >> 5;  // 32 x 8
#pragma unroll
  for (int i = 0; i < 4; ++i) {
    int row = y + i * 8;
    int kv = kv0 + row;
    if (kv < NKV) t[row][x] = in[((size_t)b * NKV + kv) * 384 + c0 + x];
  }
  __syncthreads();
#pragma unroll
  for (int i = 0; i < 4; ++i) {
    int row = y + i * 8;
    if (kv0 + x < NKV)
      out[((size_t)b * 384 + c0 + row) * NKV + kv0 + x] = t[x][row];
  }
}

// ------------- f16 MFMA flash attention, swapped-QK^T layout -------------
// grid = B*NH*49; block 256 (4 waves x 16 q rows). KVT=64.
// Q pre-scaled by 0.125*log2(e) -> softmax uses exp2 directly.
// S^T = mfma(A=K, B=Q): lane (c,g) holds S[kv = t0+ct*16+g*4+r][q = c].
// m/l tracked per q=c (4-way redundant across g). P staged per-wave in LDS
// [q][kv] with chunk swizzle ch^(q&7); read back as A-frag for PV.
__global__ __launch_bounds__(256) void attn_mfma(
    const f16* __restrict__ qp, const f16* __restrict__ kp,
    const f16* __restrict__ vt, f16* __restrict__ op) {
  __shared__ f16 Ks[64 * 64];      // [kv][d], 128B rows, chunk ch stored at ch^(kv&7)
  __shared__ f16 Vs[64 * 64];      // [d][kv], 128B rows, chunk ch stored at ch^(d&7)
  __shared__ f16 Ps[4][16 * 64];   // per-wave [q][kv], 128B rows, ch^(q&7)
  const int bid = blockIdx.x;
  const int qt = bid % 49;
  const int bh = bid / 49;
  const int h = bh % NHD, b = bh / NHD;
  const int tid = threadIdx.x;
  const int wave = tid >> 6, lane = tid & 63;
  const int c = lane & 15, g = lane >> 4;

  // Q fragments (serve as B-operand for S^T and were loaded in A-layout: same regs)
  const size_t qrow = (size_t)b * NQ + qt * 64 + wave * 16 + c;
  f16x8 qa[2];
  qa[0] = *(const f16x8*)(qp + qrow * 384 + h * 64 + g * 8);
  qa[1] = *(const f16x8*)(qp + qrow * 384 + h * 64 + 32 + g * 8);

  // staging indices: thread covers rows tid8 and tid8+32, stored chunk tch
  const int tid8 = tid >> 3, tch = tid & 7;
  const int lch = tch ^ (tid8 & 7);            // logical chunk fetched

  const f16* kbase = kp + ((size_t)b * NKV) * 384 + h * 64;
  const f16* vbase = vt + ((size_t)(b * 384 + h * 64)) * NKV;

  float mrun = -1e30f, lsum = 0.f;   // for q = c (redundant across g)
  f32x4 o[4] = {};                    // O[q=g*4+r][d=dt*16+c]
  f16* prow = &Ps[wave][0];

  for (int t0 = 0; t0 < NKV; t0 += 64) {
    __syncthreads();
    {
      // K rows t0+tid8, t0+32+tid8 (clamped); 16B chunk lch
      int kv0 = t0 + tid8; if (kv0 > NKV - 1) kv0 = NKV - 1;
      int kv1 = t0 + 32 + tid8; if (kv1 > NKV - 1) kv1 = NKV - 1;
      __builtin_amdgcn_global_load_lds(
          (const __attribute__((address_space(1))) void*)(kbase + (size_t)kv0 * 384 + lch * 8),
          (__attribute__((address_space(3))) void*)(Ks + wave * 512), 16, 0, 0);
      __builtin_amdgcn_global_load_lds(
          (const __attribute__((address_space(1))) void*)(kbase + (size_t)kv1 * 384 + lch * 8),
          (__attribute__((address_space(3))) void*)(Ks + 2048 + wave * 512), 16, 0, 0);
      // V rows (d) tid8, tid8+32; cols t0 + lch*8 (clamped to stay in row)
      int col = t0 + lch * 8; if (col > NKV - 8) col = NKV - 8;
      __builtin_amdgcn_global_load_lds(
          (const __attribute__((address_space(1))) void*)(vbase + (size_t)tid8 * NKV + col),
          (__attribute__((address_space(3))) void*)(Vs + wave * 512), 16, 0, 0);
      __builtin_amdgcn_global_load_lds(
          (const __attribute__((address_space(1))) void*)(vbase + (size_t)(32 + tid8) * NKV + col),
          (__attribute__((address_space(3))) void*)(Vs + 2048 + wave * 512), 16, 0, 0);
    }
    __syncthreads();

    // S^T tiles: s[ct] = K[t0+ct*16..+16) . Q^T, accumulated over kh
    f32x4 s[4] = {};
#pragma unroll
    for (int kh = 0; kh < 2; ++kh) {
#pragma unroll
      for (int ct = 0; ct < 4; ++ct) {
        const int row = ct * 16 + c;
        const int sch = (kh * 4 + g) ^ (row & 7);
        f16x8 kb = *(const f16x8*)(Ks + row * 64 + sch * 8);
        s[ct] = __builtin_amdgcn_mfma_f32_16x16x32_f16(kb, qa[kh], s[ct], 0, 0, 0);
      }
    }
    // tail mask
    if (t0 + 64 > NKV) {
#pragma unroll
      for (int ct = 0; ct < 4; ++ct)
#pragma unroll
        for (int r = 0; r < 4; ++r)
          if (t0 + ct * 16 + g * 4 + r >= NKV) s[ct][r] = -1e30f;
    }

    // tile max for q=c across this lane's 16 + other g groups
    float mt = s[0][0];
#pragma unroll
    for (int ct = 0; ct < 4; ++ct)
#pragma unroll
      for (int r = 0; r < 4; ++r) mt = fmaxf(mt, s[ct][r]);
    mt = fmaxf(mt, __shfl_xor(mt, 16));
    mt = fmaxf(mt, __shfl_xor(mt, 32));

    // defer-max (log2 units; P bounded by 2^8)
    unsigned long long need = __ballot(mt > mrun + 8.0f);
    if (need) {
      const float mnew = fmaxf(mrun, mt);
      const float corr = exp2f(mrun - mnew);
      mrun = mnew;
      lsum *= corr;
#pragma unroll
      for (int r = 0; r < 4; ++r) {
        const float co = __shfl(corr, g * 4 + r);
#pragma unroll
        for (int dt = 0; dt < 4; ++dt) o[dt][r] *= co;
      }
    }

    // P = exp2(S - mrun); pack f16, store to per-wave LDS; accumulate sum
    float ps = 0.f;
#pragma unroll
    for (int ct = 0; ct < 4; ++ct) {
      f16x4 pk;
#pragma unroll
      for (int r = 0; r < 4; ++r) {
        const float p = exp2f(s[ct][r] - mrun);
        ps += p;
        pk[r] = (f16)p;
      }
      const int sch = (ct * 2 + (g >> 1)) ^ (c & 7);
      *(f16x4*)(prow + c * 64 + sch * 8 + (g & 1) * 4) = pk;
    }
    ps += __shfl_xor(ps, 16);
    ps += __shfl_xor(ps, 32);
    lsum += ps;

    // PV: o[dt] += P[q][kv] * V[kv][d], two k-slices of 32
#pragma unroll
    for (int ks = 0; ks < 2; ++ks) {
      const int sp = (ks * 4 + g) ^ (c & 7);
      f16x8 pa = *(const f16x8*)(prow + c * 64 + sp * 8);
#pragma unroll
      for (int dt = 0; dt < 4; ++dt) {
        const int d = dt * 16 + c;
        f16x8 vb = *(const f16x8*)(Vs + d * 64 + sp * 8);  // (ks*4+g)^(d&7) == sp
        o[dt] = __builtin_amdgcn_mfma_f32_16x16x32_f16(pa, vb, o[dt], 0, 0, 0);
      }
    }
  }

  // epilogue: inv per q=c -> shuffle to q=g*4+r layout
  const float inv = 1.0f / lsum;
  f16* obase = op + ((size_t)(b * NQ + qt * 64 + wave * 16)) * 384 + h * 64;
#pragma unroll
  for (int r = 0; r < 4; ++r) {
    const float iv = __shfl(inv, g * 4 + r);
#pragma unroll
    for (int dt = 0; dt < 4; ++dt)
      obase[(size_t)(g * 4 + r) * 384 + dt * 16 + c] = (f16)(o[dt][r] * iv);
  }
}

extern "C" void kernel_launch(void* const* d_in, const int* in_sizes, int n_in,
                              void* d_out, int out_size, void* d_ws, size_t ws_size,
                              hipStream_t stream) {
  const float* inputs_q  = (const float*)d_in[0];
  const float* inputs_kv = (const float*)d_in[1];
  const float* out_kern  = (const float*)d_in[2];
  const float* q_dwk = (const float*)d_in[3];
  const float* q_bs  = (const float*)d_in[4];
  const float* q_bb  = (const float*)d_in[5];
  const float* q_bm  = (const float*)d_in[6];
  const float* q_bv  = (const float*)d_in[7];
  const float* q_pwk = (const float*)d_in[8];
  const float* k_dwk = (const float*)d_in[9];
  const float* k_bs  = (const float*)d_in[10];
  const float* k_bb  = (const float*)d_in[11];
  const float* k_bm  = (const float*)d_in[12];
  const float* k_bv  = (const float*)d_in[13];
  const float* k_pwk = (const float*)d_in[14];
  const float* v_dwk = (const float*)d_in[15];
  const float* v_bs  = (const float*)d_in[16];
  const float* v_bb  = (const float*)d_in[17];
  const float* v_bm  = (const float*)d_in[18];
  const float* v_bv  = (const float*)d_in[19];
  const float* v_pwk = (const float*)d_in[20];

  char* wsb = (char*)d_ws;
  f16* qdw = (f16*)(wsb + 0);             // 25088*384 f16
  f16* kdw = (f16*)(wsb + 19267584);      // 6272*384 f16
  f16* vdw = (f16*)(wsb + 24084480);      // 6272*384 f16
  f16* qf  = (f16*)(wsb + 28901376);      // 25088*384 f16
  f16* kf  = (f16*)(wsb + 48168960);      // 6272*384 f16
  f16* vf  = (f16*)(wsb + 52985856);      // 6272*384 f16
  f16* vtp = (f16*)(wsb + 57802752);      // 8*384*784 f16
  f16* of  = (f16*)(wsb + 62619648);      // 25088*384 f16
  f16* wqt = (f16*)(wsb + 81887232);      // 384*384 f16 x4
  f16* wkt = (f16*)(wsb + 82182144);
  f16* wvt = (f16*)(wsb + 82477056);
  f16* wot = (f16*)(wsb + 82771968);

  // 0. weight transpose-convert
  convert_w<<<dim3(12, 12, 4), 256, 0, stream>>>(
      q_pwk, k_pwk, v_pwk, out_kern, wqt, wkt, wvt, wot);
  // 1. depthwise + BN -> f16
  dw_bn_s1<<<9408, 256, 0, stream>>>(inputs_q, q_dwk, q_bs, q_bb, q_bm, q_bv, qdw);
  dw_bn_s2_kv<<<2352, 256, 0, stream>>>(inputs_kv,
      k_dwk, k_bs, k_bb, k_bm, k_bv,
      v_dwk, v_bs, v_bb, v_bm, v_bv,
      kdw, vdw);
  // 2. pointwise GEMMs (q folded with 1/8 * log2e for exp2 softmax)
  gemm_mfma<1><<<dim3(196, 6), 256, 0, stream>>>(qdw, wqt, nullptr, qf, 0.125f * LOG2E);
  gemm_mfma<1><<<dim3(49, 6), 256, 0, stream>>>(kdw, wkt, nullptr, kf, 1.0f);
  gemm_mfma<1><<<dim3(49, 6), 256, 0, stream>>>(vdw, wvt, nullptr, vf, 1.0f);
  // 3. V transpose per batch
  transpose_f16<<<dim3(25, 12, 8), 256, 0, stream>>>(vf, vtp);
  // 4. MFMA attention (swapped layout) -> f16 O
  attn_mfma<<<BB * NHD * 49, 256, 0, stream>>>(qf, kf, vtp, of);
  // 5. output projection (MFMA, fp32 out)
  gemm_mfma<0><<<dim3(196, 6), 256, 0, stream>>>(of, wot, (float*)d_out, nullptr, 1.0f);
}

// Round 6
// 182.332 us; speedup vs baseline: 5.5695x; 1.0800x over previous
//
#include <hip/hip_runtime.h>
#include <hip/hip_bf16.h>
#include <hip/hip_fp16.h>

// Problem constants
#define BB 8
#define HH 56
#define WW 56
#define CC 384
#define NHD 6
#define DD 64
#define HK 28
#define WK 28
#define NQ (HH*WW)       // 3136
#define NKV (HK*WK)      // 784
#define NTOK (BB*NQ)     // 25088
#define NTOKKV (BB*NKV)  // 6272
#define BN_EPS 1e-5f
#define LOG2E 1.44269504f

typedef _Float16 f16;
typedef _Float16 f16x4 __attribute__((ext_vector_type(4)));
typedef _Float16 f16x8 __attribute__((ext_vector_type(8)));
typedef float f32x4 __attribute__((ext_vector_type(4)));

__device__ __forceinline__ float fast_exp2(float x) {
#if __has_builtin(__builtin_amdgcn_exp2f)
  return __builtin_amdgcn_exp2f(x);   // v_exp_f32 (2^x)
#else
  return __expf(x * 0.69314718056f);
#endif
}

// ---------------- depthwise conv + BN, stride 1 (q path), f16 out ----------------
__global__ __launch_bounds__(256) void dw_bn_s1(
    const float* __restrict__ in, const float* __restrict__ w,
    const float* __restrict__ bns, const float* __restrict__ bnb,
    const float* __restrict__ bnm, const float* __restrict__ bnv,
    f16* __restrict__ out) {
  int idx = blockIdx.x * 256 + threadIdx.x;      // < NTOK*96
  int pix = idx / 96;
  int c = (idx % 96) * 4;
  int b = pix / (HH * WW);
  int p = pix % (HH * WW);
  int y = p / WW, x = p % WW;
  float ax = 0.f, ay = 0.f, az = 0.f, aw = 0.f;
#pragma unroll
  for (int kh = 0; kh < 3; ++kh) {
    int iy = y + kh - 1;
    if ((unsigned)iy >= (unsigned)HH) continue;
#pragma unroll
    for (int kw = 0; kw < 3; ++kw) {
      int ix = x + kw - 1;
      if ((unsigned)ix >= (unsigned)WW) continue;
      const float4 v = *(const float4*)(in + (((size_t)(b * HH + iy) * WW + ix) * CC + c));
      const float4 wk = *(const float4*)(w + ((kh * 3 + kw) * CC + c));
      ax = fmaf(v.x, wk.x, ax); ay = fmaf(v.y, wk.y, ay);
      az = fmaf(v.z, wk.z, az); aw = fmaf(v.w, wk.w, aw);
    }
  }
  const float4 s = *(const float4*)(bns + c);
  const float4 bi = *(const float4*)(bnb + c);
  const float4 m = *(const float4*)(bnm + c);
  const float4 va = *(const float4*)(bnv + c);
  f16x4 r;
  float g;
  g = s.x * rsqrtf(va.x + BN_EPS); r[0] = (f16)fmaf(ax - m.x, g, bi.x);
  g = s.y * rsqrtf(va.y + BN_EPS); r[1] = (f16)fmaf(ay - m.y, g, bi.y);
  g = s.z * rsqrtf(va.z + BN_EPS); r[2] = (f16)fmaf(az - m.z, g, bi.z);
  g = s.w * rsqrtf(va.w + BN_EPS); r[3] = (f16)fmaf(aw - m.w, g, bi.w);
  *(f16x4*)(out + (size_t)pix * CC + c) = r;
}

// -------- fused depthwise conv + BN, stride 2, k and v from same input, f16 out --------
__global__ __launch_bounds__(256) void dw_bn_s2_kv(
    const float* __restrict__ in,
    const float* __restrict__ wk_, const float* __restrict__ kbs, const float* __restrict__ kbb,
    const float* __restrict__ kbm, const float* __restrict__ kbv,
    const float* __restrict__ wv_, const float* __restrict__ vbs, const float* __restrict__ vbb,
    const float* __restrict__ vbm, const float* __restrict__ vbv,
    f16* __restrict__ outk, f16* __restrict__ outv) {
  int idx = blockIdx.x * 256 + threadIdx.x;      // < NTOKKV*96
  int pix = idx / 96;
  int c = (idx % 96) * 4;
  int b = pix / (HK * WK);
  int p = pix % (HK * WK);
  int oy = p / WK, ox = p % WK;
  float kx = 0, ky = 0, kz = 0, kw4 = 0;
  float vx = 0, vy = 0, vz = 0, vw4 = 0;
#pragma unroll
  for (int kh = 0; kh < 3; ++kh) {
    int iy = oy * 2 + kh;
    if (iy >= HH) continue;
#pragma unroll
    for (int kwi = 0; kwi < 3; ++kwi) {
      int ix = ox * 2 + kwi;
      if (ix >= WW) continue;
      const float4 v = *(const float4*)(in + (((size_t)(b * HH + iy) * WW + ix) * CC + c));
      const float4 a = *(const float4*)(wk_ + ((kh * 3 + kwi) * CC + c));
      const float4 bq = *(const float4*)(wv_ + ((kh * 3 + kwi) * CC + c));
      kx = fmaf(v.x, a.x, kx); ky = fmaf(v.y, a.y, ky);
      kz = fmaf(v.z, a.z, kz); kw4 = fmaf(v.w, a.w, kw4);
      vx = fmaf(v.x, bq.x, vx); vy = fmaf(v.y, bq.y, vy);
      vz = fmaf(v.z, bq.z, vz); vw4 = fmaf(v.w, bq.w, vw4);
    }
  }
  {
    const float4 s = *(const float4*)(kbs + c);
    const float4 bi = *(const float4*)(kbb + c);
    const float4 m = *(const float4*)(kbm + c);
    const float4 va = *(const float4*)(kbv + c);
    f16x4 r; float g;
    g = s.x * rsqrtf(va.x + BN_EPS); r[0] = (f16)fmaf(kx - m.x, g, bi.x);
    g = s.y * rsqrtf(va.y + BN_EPS); r[1] = (f16)fmaf(ky - m.y, g, bi.y);
    g = s.z * rsqrtf(va.z + BN_EPS); r[2] = (f16)fmaf(kz - m.z, g, bi.z);
    g = s.w * rsqrtf(va.w + BN_EPS); r[3] = (f16)fmaf(kw4 - m.w, g, bi.w);
    *(f16x4*)(outk + (size_t)pix * CC + c) = r;
  }
  {
    const float4 s = *(const float4*)(vbs + c);
    const float4 bi = *(const float4*)(vbb + c);
    const float4 m = *(const float4*)(vbm + c);
    const float4 va = *(const float4*)(vbv + c);
    f16x4 r; float g;
    g = s.x * rsqrtf(va.x + BN_EPS); r[0] = (f16)fmaf(vx - m.x, g, bi.x);
    g = s.y * rsqrtf(va.y + BN_EPS); r[1] = (f16)fmaf(vy - m.y, g, bi.y);
    g = s.z * rsqrtf(va.z + BN_EPS); r[2] = (f16)fmaf(vz - m.z, g, bi.z);
    g = s.w * rsqrtf(va.w + BN_EPS); r[3] = (f16)fmaf(vw4 - m.w, g, bi.w);
    *(f16x4*)(outv + (size_t)pix * CC + c) = r;
  }
}

// ---- transpose-convert 4 weight matrices: fp32 [384(k)][384(n)] -> f16 [n][k] ----
__global__ __launch_bounds__(256) void convert_w(
    const float* __restrict__ w0, const float* __restrict__ w1,
    const float* __restrict__ w2, const float* __restrict__ w3,
    f16* __restrict__ o0, f16* __restrict__ o1,
    f16* __restrict__ o2, f16* __restrict__ o3) {
  const float* src = blockIdx.z == 0 ? w0 : blockIdx.z == 1 ? w1 : blockIdx.z == 2 ? w2 : w3;
  f16* dst = blockIdx.z == 0 ? o0 : blockIdx.z == 1 ? o1 : blockIdx.z == 2 ? o2 : o3;
  __shared__ float t[32][33];
  const int k0 = blockIdx.x * 32, n0 = blockIdx.y * 32;
  const int x = threadIdx.x & 31, y = threadIdx.x >> 5;
#pragma unroll
  for (int i = 0; i < 4; ++i) t[y + i * 8][x] = src[(size_t)(k0 + y + i * 8) * 384 + n0 + x];
  __syncthreads();
#pragma unroll
  for (int i = 0; i < 4; ++i)
    dst[(size_t)(n0 + y + i * 8) * 384 + k0 + x] = (f16)t[x][y + i * 8];
}

// ------------- f16 MFMA GEMM body: C[M,384] = scale * A[M,384] @ Bt^T -------------
template <int OF16>
__device__ __forceinline__ void gemm_body(
    const f16* __restrict__ A, const f16* __restrict__ Bt,
    float* __restrict__ Cf, f16* __restrict__ Ch, float scale,
    int row0, int col0) {
  __shared__ f16 As[128 * 32];   // [row][k], 64 B per row
  __shared__ f16 Bs[64 * 32];    // [col][k], 64 B per col
  const int tid = threadIdx.x;
  const int wave = tid >> 6, lane = tid & 63;
  const int c = lane & 15, g = lane >> 4;
  const int wr = wave >> 1, wc = wave & 1;

  f32x4 acc[4][2] = {};

  for (int k0 = 0; k0 < 384; k0 += 32) {
    __syncthreads();
    {
      int i0 = wave * 64 + lane;
      const f16* s0 = A + (size_t)(row0 + (i0 >> 2)) * 384 + k0 + (i0 & 3) * 8;
      __builtin_amdgcn_global_load_lds(
          (const __attribute__((address_space(1))) void*)s0,
          (__attribute__((address_space(3))) void*)(As + wave * 512), 16, 0, 0);
      int i1 = 256 + wave * 64 + lane;
      const f16* s1 = A + (size_t)(row0 + (i1 >> 2)) * 384 + k0 + (i1 & 3) * 8;
      __builtin_amdgcn_global_load_lds(
          (const __attribute__((address_space(1))) void*)s1,
          (__attribute__((address_space(3))) void*)(As + 2048 + wave * 512), 16, 0, 0);
      int ib = wave * 64 + lane;
      const f16* sb = Bt + (size_t)(col0 + (ib >> 2)) * 384 + k0 + (ib & 3) * 8;
      __builtin_amdgcn_global_load_lds(
          (const __attribute__((address_space(1))) void*)sb,
          (__attribute__((address_space(3))) void*)(Bs + wave * 512), 16, 0, 0);
    }
    __syncthreads();

    f16x8 bfr[2];
#pragma unroll
    for (int n = 0; n < 2; ++n)
      bfr[n] = *(const f16x8*)(Bs + (size_t)(wc * 32 + n * 16 + c) * 32 + g * 8);
#pragma unroll
    for (int m = 0; m < 4; ++m) {
      f16x8 af = *(const f16x8*)(As + (size_t)(wr * 64 + m * 16 + c) * 32 + g * 8);
      acc[m][0] = __builtin_amdgcn_mfma_f32_16x16x32_f16(af, bfr[0], acc[m][0], 0, 0, 0);
      acc[m][1] = __builtin_amdgcn_mfma_f32_16x16x32_f16(af, bfr[1], acc[m][1], 0, 0, 0);
    }
  }

#pragma unroll
  for (int m = 0; m < 4; ++m)
#pragma unroll
    for (int n = 0; n < 2; ++n)
#pragma unroll
      for (int r = 0; r < 4; ++r) {
        const size_t row = row0 + wr * 64 + m * 16 + g * 4 + r;
        const size_t col = col0 + wc * 32 + n * 16 + c;
        if (OF16) Ch[row * 384 + col] = (f16)(acc[m][n][r] * scale);
        else      Cf[row * 384 + col] = acc[m][n][r] * scale;
      }
}

template <int OF16>
__global__ __launch_bounds__(256) void gemm_mfma(
    const f16* __restrict__ A, const f16* __restrict__ Bt,
    float* __restrict__ Cf, f16* __restrict__ Ch, float scale) {
  gemm_body<OF16>(A, Bt, Cf, Ch, scale, blockIdx.x * 128, blockIdx.y * 64);
}

// k and v pointwise GEMMs in one launch (blockIdx.z picks)
__global__ __launch_bounds__(256) void gemm_kv(
    const f16* __restrict__ A0, const f16* __restrict__ B0, f16* __restrict__ C0,
    const f16* __restrict__ A1, const f16* __restrict__ B1, f16* __restrict__ C1) {
  if (blockIdx.z == 0)
    gemm_body<1>(A0, B0, nullptr, C0, 1.0f, blockIdx.x * 128, blockIdx.y * 64);
  else
    gemm_body<1>(A1, B1, nullptr, C1, 1.0f, blockIdx.x * 128, blockIdx.y * 64);
}

// ------------- per-batch transpose: in [b*784+kv][384] -> out [b*384+c][784] -------------
__global__ __launch_bounds__(256) void transpose_f16(
    const f16* __restrict__ in, f16* __restrict__ out) {
  __shared__ f16 t[32][33];
  const int b = blockIdx.z;
  const int kv0 = blockIdx.x * 32, c0 = blockIdx.y * 32;
  const int x = threadIdx.x & 31, y = threadIdx.x >> 5;  // 32 x 8
#pragma unroll
  for (int i = 0; i < 4; ++i) {
    int row = y + i * 8;
    int kv = kv0 + row;
    if (kv < NKV) t[row][x] = in[((size_t)b * NKV + kv) * 384 + c0 + x];
  }
  __syncthreads();
#pragma unroll
  for (int i = 0; i < 4; ++i) {
    int row = y + i * 8;
    if (kv0 + x < NKV)
      out[((size_t)b * 384 + c0 + row) * NKV + kv0 + x] = t[x][row];
  }
}

// ------------- f16 MFMA flash attention, swapped-QK^T layout (R4 sync structure) -------------
// grid = B*NH*49; block 256 (4 waves x 16 q rows). KVT=64.
// Q pre-scaled by 0.125*log2(e) -> softmax uses native exp2.
// S^T = mfma(A=K, B=Q): lane (c,g) holds S[kv = t0+ct*16+g*4+r][q = c].
__global__ __launch_bounds__(256) void attn_mfma(
    const f16* __restrict__ qp, const f16* __restrict__ kp,
    const f16* __restrict__ vt, f16* __restrict__ op) {
  __shared__ f16 Ks[64 * 64];      // [kv][d], 128B rows, chunk ch stored at ch^(kv&7)
  __shared__ f16 Vs[64 * 64];      // [d][kv], 128B rows, chunk ch stored at ch^(d&7)
  __shared__ f16 Ps[4][16 * 64];   // per-wave [q][kv], 128B rows, ch^(q&7)
  const int bid = blockIdx.x;
  const int qt = bid % 49;
  const int bh = bid / 49;
  const int h = bh % NHD, b = bh / NHD;
  const int tid = threadIdx.x;
  const int wave = tid >> 6, lane = tid & 63;
  const int c = lane & 15, g = lane >> 4;

  const size_t qrow = (size_t)b * NQ + qt * 64 + wave * 16 + c;
  f16x8 qa[2];
  qa[0] = *(const f16x8*)(qp + qrow * 384 + h * 64 + g * 8);
  qa[1] = *(const f16x8*)(qp + qrow * 384 + h * 64 + 32 + g * 8);

  const int tid8 = tid >> 3, tch = tid & 7;
  const int lch = tch ^ (tid8 & 7);            // logical chunk fetched

  const f16* kbase = kp + ((size_t)b * NKV) * 384 + h * 64;
  const f16* vbase = vt + ((size_t)(b * 384 + h * 64)) * NKV;

  float mrun = -1e30f, lsum = 0.f;   // for q = c (redundant across g)
  f32x4 o[4] = {};                    // O[q=g*4+r][d=dt*16+c]
  f16* prow = &Ps[wave][0];

  for (int t0 = 0; t0 < NKV; t0 += 64) {
    __syncthreads();
    {
      int kv0 = t0 + tid8; if (kv0 > NKV - 1) kv0 = NKV - 1;
      int kv1 = t0 + 32 + tid8; if (kv1 > NKV - 1) kv1 = NKV - 1;
      __builtin_amdgcn_global_load_lds(
          (const __attribute__((address_space(1))) void*)(kbase + (size_t)kv0 * 384 + lch * 8),
          (__attribute__((address_space(3))) void*)(Ks + wave * 512), 16, 0, 0);
      __builtin_amdgcn_global_load_lds(
          (const __attribute__((address_space(1))) void*)(kbase + (size_t)kv1 * 384 + lch * 8),
          (__attribute__((address_space(3))) void*)(Ks + 2048 + wave * 512), 16, 0, 0);
      int col = t0 + lch * 8; if (col > NKV - 8) col = NKV - 8;
      __builtin_amdgcn_global_load_lds(
          (const __attribute__((address_space(1))) void*)(vbase + (size_t)tid8 * NKV + col),
          (__attribute__((address_space(3))) void*)(Vs + wave * 512), 16, 0, 0);
      __builtin_amdgcn_global_load_lds(
          (const __attribute__((address_space(1))) void*)(vbase + (size_t)(32 + tid8) * NKV + col),
          (__attribute__((address_space(3))) void*)(Vs + 2048 + wave * 512), 16, 0, 0);
    }
    __syncthreads();

    // S^T tiles: s[ct] = K[t0+ct*16..+16) . Q^T, accumulated over kh
    f32x4 s[4] = {};
#pragma unroll
    for (int kh = 0; kh < 2; ++kh) {
#pragma unroll
      for (int ct = 0; ct < 4; ++ct) {
        const int row = ct * 16 + c;
        const int sch = (kh * 4 + g) ^ (row & 7);
        f16x8 kb = *(const f16x8*)(Ks + row * 64 + sch * 8);
        s[ct] = __builtin_amdgcn_mfma_f32_16x16x32_f16(kb, qa[kh], s[ct], 0, 0, 0);
      }
    }
    // tail mask
    if (t0 + 64 > NKV) {
#pragma unroll
      for (int ct = 0; ct < 4; ++ct)
#pragma unroll
        for (int r = 0; r < 4; ++r)
          if (t0 + ct * 16 + g * 4 + r >= NKV) s[ct][r] = -1e30f;
    }

    // tile max for q=c
    float mt = s[0][0];
#pragma unroll
    for (int ct = 0; ct < 4; ++ct)
#pragma unroll
      for (int r = 0; r < 4; ++r) mt = fmaxf(mt, s[ct][r]);
    mt = fmaxf(mt, __shfl_xor(mt, 16));
    mt = fmaxf(mt, __shfl_xor(mt, 32));

    // defer-max (log2 units; P bounded by 2^8)
    unsigned long long need = __ballot(mt > mrun + 8.0f);
    if (need) {
      const float mnew = fmaxf(mrun, mt);
      const float corr = fast_exp2(mrun - mnew);
      mrun = mnew;
      lsum *= corr;
#pragma unroll
      for (int r = 0; r < 4; ++r) {
        const float co = __shfl(corr, g * 4 + r);
#pragma unroll
        for (int dt = 0; dt < 4; ++dt) o[dt][r] *= co;
      }
    }

    // P = exp2(S - mrun); pack f16, store to per-wave LDS; accumulate sum
    float ps = 0.f;
#pragma unroll
    for (int ct = 0; ct < 4; ++ct) {
      f16x4 pk;
#pragma unroll
      for (int r = 0; r < 4; ++r) {
        const float p = fast_exp2(s[ct][r] - mrun);
        ps += p;
        pk[r] = (f16)p;
      }
      const int sch = (ct * 2 + (g >> 1)) ^ (c & 7);
      *(f16x4*)(prow + c * 64 + sch * 8 + (g & 1) * 4) = pk;
    }
    ps += __shfl_xor(ps, 16);
    ps += __shfl_xor(ps, 32);
    lsum += ps;

    // PV: o[dt] += P[q][kv] * V[kv][d], two k-slices of 32
#pragma unroll
    for (int ks = 0; ks < 2; ++ks) {
      const int sp = (ks * 4 + g) ^ (c & 7);
      f16x8 pa = *(const f16x8*)(prow + c * 64 + sp * 8);
#pragma unroll
      for (int dt = 0; dt < 4; ++dt) {
        const int d = dt * 16 + c;
        f16x8 vb = *(const f16x8*)(Vs + d * 64 + sp * 8);  // (ks*4+g)^(d&7) == sp
        o[dt] = __builtin_amdgcn_mfma_f32_16x16x32_f16(pa, vb, o[dt], 0, 0, 0);
      }
    }
  }

  // epilogue: inv per q=c -> shuffle to q=g*4+r layout
  const float inv = 1.0f / lsum;
  f16* obase = op + ((size_t)(b * NQ + qt * 64 + wave * 16)) * 384 + h * 64;
#pragma unroll
  for (int r = 0; r < 4; ++r) {
    const float iv = __shfl(inv, g * 4 + r);
#pragma unroll
    for (int dt = 0; dt < 4; ++dt)
      obase[(size_t)(g * 4 + r) * 384 + dt * 16 + c] = (f16)(o[dt][r] * iv);
  }
}

extern "C" void kernel_launch(void* const* d_in, const int* in_sizes, int n_in,
                              void* d_out, int out_size, void* d_ws, size_t ws_size,
                              hipStream_t stream) {
  const float* inputs_q  = (const float*)d_in[0];
  const float* inputs_kv = (const float*)d_in[1];
  const float* out_kern  = (const float*)d_in[2];
  const float* q_dwk = (const float*)d_in[3];
  const float* q_bs  = (const float*)d_in[4];
  const float* q_bb  = (const float*)d_in[5];
  const float* q_bm  = (const float*)d_in[6];
  const float* q_bv  = (const float*)d_in[7];
  const float* q_pwk = (const float*)d_in[8];
  const float* k_dwk = (const float*)d_in[9];
  const float* k_bs  = (const float*)d_in[10];
  const float* k_bb  = (const float*)d_in[11];
  const float* k_bm  = (const float*)d_in[12];
  const float* k_bv  = (const float*)d_in[13];
  const float* k_pwk = (const float*)d_in[14];
  const float* v_dwk = (const float*)d_in[15];
  const float* v_bs  = (const float*)d_in[16];
  const float* v_bb  = (const float*)d_in[17];
  const float* v_bm  = (const float*)d_in[18];
  const float* v_bv  = (const float*)d_in[19];
  const float* v_pwk = (const float*)d_in[20];

  char* wsb = (char*)d_ws;
  f16* qdw = (f16*)(wsb + 0);             // 25088*384 f16
  f16* kdw = (f16*)(wsb + 19267584);      // 6272*384 f16
  f16* vdw = (f16*)(wsb + 24084480);      // 6272*384 f16
  f16* qf  = (f16*)(wsb + 28901376);      // 25088*384 f16
  f16* kf  = (f16*)(wsb + 48168960);      // 6272*384 f16
  f16* vf  = (f16*)(wsb + 52985856);      // 6272*384 f16
  f16* vtp = (f16*)(wsb + 57802752);      // 8*384*784 f16
  f16* of  = (f16*)(wsb + 62619648);      // 25088*384 f16
  f16* wqt = (f16*)(wsb + 81887232);      // 384*384 f16 x4
  f16* wkt = (f16*)(wsb + 82182144);
  f16* wvt = (f16*)(wsb + 82477056);
  f16* wot = (f16*)(wsb + 82771968);

  // 0. weight transpose-convert
  convert_w<<<dim3(12, 12, 4), 256, 0, stream>>>(
      q_pwk, k_pwk, v_pwk, out_kern, wqt, wkt, wvt, wot);
  // 1. depthwise + BN -> f16
  dw_bn_s1<<<9408, 256, 0, stream>>>(inputs_q, q_dwk, q_bs, q_bb, q_bm, q_bv, qdw);
  dw_bn_s2_kv<<<2352, 256, 0, stream>>>(inputs_kv,
      k_dwk, k_bs, k_bb, k_bm, k_bv,
      v_dwk, v_bs, v_bb, v_bm, v_bv,
      kdw, vdw);
  // 2. pointwise GEMMs (q folded with 1/8 * log2e for exp2 softmax)
  gemm_mfma<1><<<dim3(196, 6), 256, 0, stream>>>(qdw, wqt, nullptr, qf, 0.125f * LOG2E);
  gemm_kv<<<dim3(49, 6, 2), 256, 0, stream>>>(kdw, wkt, kf, vdw, wvt, vf);
  // 3. V transpose per batch
  transpose_f16<<<dim3(25, 12, 8), 256, 0, stream>>>(vf, vtp);
  // 4. MFMA attention (swapped layout) -> f16 O
  attn_mfma<<<BB * NHD * 49, 256, 0, stream>>>(qf, kf, vtp, of);
  // 5. output projection (MFMA, fp32 out)
  gemm_mfma<0><<<dim3(196, 6), 256, 0, stream>>>(of, wot, (float*)d_out, nullptr, 1.0f);
}

// Round 7
// 175.967 us; speedup vs baseline: 5.7710x; 1.0362x over previous
//
#include <hip/hip_runtime.h>
#include <hip/hip_bf16.h>
#include <hip/hip_fp16.h>

// Problem constants
#define BB 8
#define HH 56
#define WW 56
#define CC 384
#define NHD 6
#define DD 64
#define HK 28
#define WK 28
#define NQ (HH*WW)       // 3136
#define NKV (HK*WK)      // 784
#define NTOK (BB*NQ)     // 25088
#define NTOKKV (BB*NKV)  // 6272
#define BN_EPS 1e-5f
#define LOG2E 1.44269504f

typedef _Float16 f16;
typedef _Float16 f16x4 __attribute__((ext_vector_type(4)));
typedef _Float16 f16x8 __attribute__((ext_vector_type(8)));
typedef float f32x4 __attribute__((ext_vector_type(4)));

__device__ __forceinline__ float fast_exp2(float x) {
#if __has_builtin(__builtin_amdgcn_exp2f)
  return __builtin_amdgcn_exp2f(x);   // v_exp_f32 (2^x)
#else
  return __expf(x * 0.69314718056f);
#endif
}

// ---------------- depthwise conv + BN, stride 1 (q path), f16 out ----------------
__global__ __launch_bounds__(256) void dw_bn_s1(
    const float* __restrict__ in, const float* __restrict__ w,
    const float* __restrict__ bns, const float* __restrict__ bnb,
    const float* __restrict__ bnm, const float* __restrict__ bnv,
    f16* __restrict__ out) {
  int idx = blockIdx.x * 256 + threadIdx.x;      // < NTOK*96
  int pix = idx / 96;
  int c = (idx % 96) * 4;
  int b = pix / (HH * WW);
  int p = pix % (HH * WW);
  int y = p / WW, x = p % WW;
  float ax = 0.f, ay = 0.f, az = 0.f, aw = 0.f;
#pragma unroll
  for (int kh = 0; kh < 3; ++kh) {
    int iy = y + kh - 1;
    if ((unsigned)iy >= (unsigned)HH) continue;
#pragma unroll
    for (int kw = 0; kw < 3; ++kw) {
      int ix = x + kw - 1;
      if ((unsigned)ix >= (unsigned)WW) continue;
      const float4 v = *(const float4*)(in + (((size_t)(b * HH + iy) * WW + ix) * CC + c));
      const float4 wk = *(const float4*)(w + ((kh * 3 + kw) * CC + c));
      ax = fmaf(v.x, wk.x, ax); ay = fmaf(v.y, wk.y, ay);
      az = fmaf(v.z, wk.z, az); aw = fmaf(v.w, wk.w, aw);
    }
  }
  const float4 s = *(const float4*)(bns + c);
  const float4 bi = *(const float4*)(bnb + c);
  const float4 m = *(const float4*)(bnm + c);
  const float4 va = *(const float4*)(bnv + c);
  f16x4 r;
  float g;
  g = s.x * rsqrtf(va.x + BN_EPS); r[0] = (f16)fmaf(ax - m.x, g, bi.x);
  g = s.y * rsqrtf(va.y + BN_EPS); r[1] = (f16)fmaf(ay - m.y, g, bi.y);
  g = s.z * rsqrtf(va.z + BN_EPS); r[2] = (f16)fmaf(az - m.z, g, bi.z);
  g = s.w * rsqrtf(va.w + BN_EPS); r[3] = (f16)fmaf(aw - m.w, g, bi.w);
  *(f16x4*)(out + (size_t)pix * CC + c) = r;
}

// -------- fused depthwise conv + BN, stride 2, k and v from same input, f16 out --------
__global__ __launch_bounds__(256) void dw_bn_s2_kv(
    const float* __restrict__ in,
    const float* __restrict__ wk_, const float* __restrict__ kbs, const float* __restrict__ kbb,
    const float* __restrict__ kbm, const float* __restrict__ kbv,
    const float* __restrict__ wv_, const float* __restrict__ vbs, const float* __restrict__ vbb,
    const float* __restrict__ vbm, const float* __restrict__ vbv,
    f16* __restrict__ outk, f16* __restrict__ outv) {
  int idx = blockIdx.x * 256 + threadIdx.x;      // < NTOKKV*96
  int pix = idx / 96;
  int c = (idx % 96) * 4;
  int b = pix / (HK * WK);
  int p = pix % (HK * WK);
  int oy = p / WK, ox = p % WK;
  float kx = 0, ky = 0, kz = 0, kw4 = 0;
  float vx = 0, vy = 0, vz = 0, vw4 = 0;
#pragma unroll
  for (int kh = 0; kh < 3; ++kh) {
    int iy = oy * 2 + kh;
    if (iy >= HH) continue;
#pragma unroll
    for (int kwi = 0; kwi < 3; ++kwi) {
      int ix = ox * 2 + kwi;
      if (ix >= WW) continue;
      const float4 v = *(const float4*)(in + (((size_t)(b * HH + iy) * WW + ix) * CC + c));
      const float4 a = *(const float4*)(wk_ + ((kh * 3 + kwi) * CC + c));
      const float4 bq = *(const float4*)(wv_ + ((kh * 3 + kwi) * CC + c));
      kx = fmaf(v.x, a.x, kx); ky = fmaf(v.y, a.y, ky);
      kz = fmaf(v.z, a.z, kz); kw4 = fmaf(v.w, a.w, kw4);
      vx = fmaf(v.x, bq.x, vx); vy = fmaf(v.y, bq.y, vy);
      vz = fmaf(v.z, bq.z, vz); vw4 = fmaf(v.w, bq.w, vw4);
    }
  }
  {
    const float4 s = *(const float4*)(kbs + c);
    const float4 bi = *(const float4*)(kbb + c);
    const float4 m = *(const float4*)(kbm + c);
    const float4 va = *(const float4*)(kbv + c);
    f16x4 r; float g;
    g = s.x * rsqrtf(va.x + BN_EPS); r[0] = (f16)fmaf(kx - m.x, g, bi.x);
    g = s.y * rsqrtf(va.y + BN_EPS); r[1] = (f16)fmaf(ky - m.y, g, bi.y);
    g = s.z * rsqrtf(va.z + BN_EPS); r[2] = (f16)fmaf(kz - m.z, g, bi.z);
    g = s.w * rsqrtf(va.w + BN_EPS); r[3] = (f16)fmaf(kw4 - m.w, g, bi.w);
    *(f16x4*)(outk + (size_t)pix * CC + c) = r;
  }
  {
    const float4 s = *(const float4*)(vbs + c);
    const float4 bi = *(const float4*)(vbb + c);
    const float4 m = *(const float4*)(vbm + c);
    const float4 va = *(const float4*)(vbv + c);
    f16x4 r; float g;
    g = s.x * rsqrtf(va.x + BN_EPS); r[0] = (f16)fmaf(vx - m.x, g, bi.x);
    g = s.y * rsqrtf(va.y + BN_EPS); r[1] = (f16)fmaf(vy - m.y, g, bi.y);
    g = s.z * rsqrtf(va.z + BN_EPS); r[2] = (f16)fmaf(vz - m.z, g, bi.z);
    g = s.w * rsqrtf(va.w + BN_EPS); r[3] = (f16)fmaf(vw4 - m.w, g, bi.w);
    *(f16x4*)(outv + (size_t)pix * CC + c) = r;
  }
}

// ---- transpose-convert 4 weight matrices: fp32 [384(k)][384(n)] -> f16 [n][k] ----
__global__ __launch_bounds__(256) void convert_w(
    const float* __restrict__ w0, const float* __restrict__ w1,
    const float* __restrict__ w2, const float* __restrict__ w3,
    f16* __restrict__ o0, f16* __restrict__ o1,
    f16* __restrict__ o2, f16* __restrict__ o3) {
  const float* src = blockIdx.z == 0 ? w0 : blockIdx.z == 1 ? w1 : blockIdx.z == 2 ? w2 : w3;
  f16* dst = blockIdx.z == 0 ? o0 : blockIdx.z == 1 ? o1 : blockIdx.z == 2 ? o2 : o3;
  __shared__ float t[32][33];
  const int k0 = blockIdx.x * 32, n0 = blockIdx.y * 32;
  const int x = threadIdx.x & 31, y = threadIdx.x >> 5;
#pragma unroll
  for (int i = 0; i < 4; ++i) t[y + i * 8][x] = src[(size_t)(k0 + y + i * 8) * 384 + n0 + x];
  __syncthreads();
#pragma unroll
  for (int i = 0; i < 4; ++i)
    dst[(size_t)(n0 + y + i * 8) * 384 + k0 + x] = (f16)t[x][y + i * 8];
}

// ------------- f16 MFMA GEMM body (m97-style 128x128 tile, 4 waves, 4x4 frags) -------------
// C[M,384] = scale * A[M,384] @ Bt^T. A row-major f16; Bt [n][k] f16.
template <int OF16>
__device__ __forceinline__ void gemm_body(
    const f16* __restrict__ A, const f16* __restrict__ Bt,
    float* __restrict__ Cf, f16* __restrict__ Ch, float scale,
    int row0, int col0) {
  __shared__ f16 As[128 * 32];   // [row][k], 64 B per row
  __shared__ f16 Bs[128 * 32];   // [col][k], 64 B per col
  const int tid = threadIdx.x;
  const int wave = tid >> 6, lane = tid & 63;
  const int c = lane & 15, g = lane >> 4;
  const int wr = wave >> 1, wc = wave & 1;     // 2x2 waves, each 64x64

  f32x4 acc[4][4] = {};

  for (int k0 = 0; k0 < 384; k0 += 32) {
    __syncthreads();
#pragma unroll
    for (int ph = 0; ph < 2; ++ph) {
      const int i = ph * 256 + wave * 64 + lane;   // chunk index: row = i>>2, ch = i&3
      const f16* sa = A + (size_t)(row0 + (i >> 2)) * 384 + k0 + (i & 3) * 8;
      __builtin_amdgcn_global_load_lds(
          (const __attribute__((address_space(1))) void*)sa,
          (__attribute__((address_space(3))) void*)(As + ph * 2048 + wave * 512), 16, 0, 0);
      const f16* sb = Bt + (size_t)(col0 + (i >> 2)) * 384 + k0 + (i & 3) * 8;
      __builtin_amdgcn_global_load_lds(
          (const __attribute__((address_space(1))) void*)sb,
          (__attribute__((address_space(3))) void*)(Bs + ph * 2048 + wave * 512), 16, 0, 0);
    }
    __syncthreads();

    f16x8 bf[4];
#pragma unroll
    for (int n = 0; n < 4; ++n)
      bf[n] = *(const f16x8*)(Bs + (size_t)(wc * 64 + n * 16 + c) * 32 + g * 8);
#pragma unroll
    for (int m = 0; m < 4; ++m) {
      f16x8 af = *(const f16x8*)(As + (size_t)(wr * 64 + m * 16 + c) * 32 + g * 8);
#pragma unroll
      for (int n = 0; n < 4; ++n)
        acc[m][n] = __builtin_amdgcn_mfma_f32_16x16x32_f16(af, bf[n], acc[m][n], 0, 0, 0);
    }
  }

  // epilogue: lane holds C[row0+wr*64+m*16+g*4+r][col0+wc*64+n*16+c]
#pragma unroll
  for (int m = 0; m < 4; ++m)
#pragma unroll
    for (int n = 0; n < 4; ++n)
#pragma unroll
      for (int r = 0; r < 4; ++r) {
        const size_t row = row0 + wr * 64 + m * 16 + g * 4 + r;
        const size_t col = col0 + wc * 64 + n * 16 + c;
        if (OF16) Ch[row * 384 + col] = (f16)(acc[m][n][r] * scale);
        else      Cf[row * 384 + col] = acc[m][n][r] * scale;
      }
}

template <int OF16>
__global__ __launch_bounds__(256) void gemm_mfma(
    const f16* __restrict__ A, const f16* __restrict__ Bt,
    float* __restrict__ Cf, f16* __restrict__ Ch, float scale) {
  gemm_body<OF16>(A, Bt, Cf, Ch, scale, blockIdx.x * 128, blockIdx.y * 128);
}

// k and v pointwise GEMMs in one launch (blockIdx.z picks)
__global__ __launch_bounds__(256) void gemm_kv(
    const f16* __restrict__ A0, const f16* __restrict__ B0, f16* __restrict__ C0,
    const f16* __restrict__ A1, const f16* __restrict__ B1, f16* __restrict__ C1) {
  if (blockIdx.z == 0)
    gemm_body<1>(A0, B0, nullptr, C0, 1.0f, blockIdx.x * 128, blockIdx.y * 128);
  else
    gemm_body<1>(A1, B1, nullptr, C1, 1.0f, blockIdx.x * 128, blockIdx.y * 128);
}

// ------------- per-batch transpose: in [b*784+kv][384] -> out [b*384+c][784] -------------
__global__ __launch_bounds__(256) void transpose_f16(
    const f16* __restrict__ in, f16* __restrict__ out) {
  __shared__ f16 t[32][33];
  const int b = blockIdx.z;
  const int kv0 = blockIdx.x * 32, c0 = blockIdx.y * 32;
  const int x = threadIdx.x & 31, y = threadIdx.x >> 5;  // 32 x 8
#pragma unroll
  for (int i = 0; i < 4; ++i) {
    int row = y + i * 8;
    int kv = kv0 + row;
    if (kv < NKV) t[row][x] = in[((size_t)b * NKV + kv) * 384 + c0 + x];
  }
  __syncthreads();
#pragma unroll
  for (int i = 0; i < 4; ++i) {
    int row = y + i * 8;
    if (kv0 + x < NKV)
      out[((size_t)b * 384 + c0 + row) * NKV + kv0 + x] = t[x][row];
  }
}

// ------------- f16 MFMA flash attention, swapped-QK^T, stage-ahead dbuf -------------
// grid = B*NH*49; block 256 (4 waves x 16 q rows). KVT=64, NT=13.
// Q pre-scaled by 0.125*log2(e) -> softmax uses native exp2.
// S^T = mfma(A=K, B=Q): lane (c,g) holds S[kv = t0+ct*16+g*4+r][q = c].
// Double-buffer with LEGAL sync: one __syncthreads per tile; STAGE(t+1) issued
// right after the barrier so loads fly across the whole compute phase.
#define NT 13
__global__ __launch_bounds__(256) void attn_mfma(
    const f16* __restrict__ qp, const f16* __restrict__ kp,
    const f16* __restrict__ vt, f16* __restrict__ op) {
  __shared__ f16 Ks[2][64 * 64];   // [buf][kv][d], 128B rows, chunk ch at ch^(kv&7)
  __shared__ f16 Vs[2][64 * 64];   // [buf][d][kv], 128B rows, chunk ch at ch^(d&7)
  __shared__ f16 Ps[4][16 * 64];   // per-wave [q][kv], 128B rows, ch^(q&7)
  const int bid = blockIdx.x;
  const int qt = bid % 49;
  const int bh = bid / 49;
  const int h = bh % NHD, b = bh / NHD;
  const int tid = threadIdx.x;
  const int wave = tid >> 6, lane = tid & 63;
  const int c = lane & 15, g = lane >> 4;

  const size_t qrow = (size_t)b * NQ + qt * 64 + wave * 16 + c;
  f16x8 qa[2];
  qa[0] = *(const f16x8*)(qp + qrow * 384 + h * 64 + g * 8);
  qa[1] = *(const f16x8*)(qp + qrow * 384 + h * 64 + 32 + g * 8);

  const int tid8 = tid >> 3, tch = tid & 7;
  const int lch = tch ^ (tid8 & 7);            // logical chunk fetched

  const f16* kbase = kp + ((size_t)b * NKV) * 384 + h * 64;
  const f16* vbase = vt + ((size_t)(b * 384 + h * 64)) * NKV;

  float mrun = -1e30f, lsum = 0.f;   // for q = c (redundant across g)
  f32x4 o[4] = {};                    // O[q=g*4+r][d=dt*16+c]
  f16* prow = &Ps[wave][0];

#define STAGE(T0, BUF) do {                                                              \
    int kv0 = (T0) + tid8; if (kv0 > NKV - 1) kv0 = NKV - 1;                             \
    int kv1 = (T0) + 32 + tid8; if (kv1 > NKV - 1) kv1 = NKV - 1;                        \
    __builtin_amdgcn_global_load_lds(                                                    \
        (const __attribute__((address_space(1))) void*)(kbase + (size_t)kv0 * 384 + lch * 8), \
        (__attribute__((address_space(3))) void*)(&Ks[BUF][0] + wave * 512), 16, 0, 0);  \
    __builtin_amdgcn_global_load_lds(                                                    \
        (const __attribute__((address_space(1))) void*)(kbase + (size_t)kv1 * 384 + lch * 8), \
        (__attribute__((address_space(3))) void*)(&Ks[BUF][0] + 2048 + wave * 512), 16, 0, 0);\
    int col = (T0) + lch * 8; if (col > NKV - 8) col = NKV - 8;                          \
    __builtin_amdgcn_global_load_lds(                                                    \
        (const __attribute__((address_space(1))) void*)(vbase + (size_t)tid8 * NKV + col),    \
        (__attribute__((address_space(3))) void*)(&Vs[BUF][0] + wave * 512), 16, 0, 0);  \
    __builtin_amdgcn_global_load_lds(                                                    \
        (const __attribute__((address_space(1))) void*)(vbase + (size_t)(32 + tid8) * NKV + col), \
        (__attribute__((address_space(3))) void*)(&Vs[BUF][0] + 2048 + wave * 512), 16, 0, 0); \
  } while (0)

  STAGE(0, 0);
  int cur = 0;

  for (int ti = 0; ti < NT; ++ti) {
    const int t0 = ti * 64;
    __syncthreads();     // buf[cur] staged (own-wave vmcnt drained) + prev readers of buf[cur^1] done
    if (ti + 1 < NT) STAGE(t0 + 64, cur ^ 1);   // prefetch next tile during compute
    const f16* ksb = &Ks[cur][0];
    const f16* vsb = &Vs[cur][0];

    // S^T tiles: s[ct] = K[t0+ct*16..+16) . Q^T, accumulated over kh
    f32x4 s[4] = {};
#pragma unroll
    for (int kh = 0; kh < 2; ++kh) {
#pragma unroll
      for (int ct = 0; ct < 4; ++ct) {
        const int row = ct * 16 + c;
        const int sch = (kh * 4 + g) ^ (row & 7);
        f16x8 kb = *(const f16x8*)(ksb + row * 64 + sch * 8);
        s[ct] = __builtin_amdgcn_mfma_f32_16x16x32_f16(kb, qa[kh], s[ct], 0, 0, 0);
      }
    }
    // tail mask
    if (t0 + 64 > NKV) {
#pragma unroll
      for (int ct = 0; ct < 4; ++ct)
#pragma unroll
        for (int r = 0; r < 4; ++r)
          if (t0 + ct * 16 + g * 4 + r >= NKV) s[ct][r] = -1e30f;
    }

    // tile max for q=c
    float mt = s[0][0];
#pragma unroll
    for (int ct = 0; ct < 4; ++ct)
#pragma unroll
      for (int r = 0; r < 4; ++r) mt = fmaxf(mt, s[ct][r]);
    mt = fmaxf(mt, __shfl_xor(mt, 16));
    mt = fmaxf(mt, __shfl_xor(mt, 32));

    // defer-max (log2 units; P bounded by 2^8)
    unsigned long long need = __ballot(mt > mrun + 8.0f);
    if (need) {
      const float mnew = fmaxf(mrun, mt);
      const float corr = fast_exp2(mrun - mnew);
      mrun = mnew;
      lsum *= corr;
#pragma unroll
      for (int r = 0; r < 4; ++r) {
        const float co = __shfl(corr, g * 4 + r);
#pragma unroll
        for (int dt = 0; dt < 4; ++dt) o[dt][r] *= co;
      }
    }

    // P = exp2(S - mrun); pack f16, store to per-wave LDS; accumulate sum
    float ps = 0.f;
#pragma unroll
    for (int ct = 0; ct < 4; ++ct) {
      f16x4 pk;
#pragma unroll
      for (int r = 0; r < 4; ++r) {
        const float p = fast_exp2(s[ct][r] - mrun);
        ps += p;
        pk[r] = (f16)p;
      }
      const int sch = (ct * 2 + (g >> 1)) ^ (c & 7);
      *(f16x4*)(prow + c * 64 + sch * 8 + (g & 1) * 4) = pk;
    }
    ps += __shfl_xor(ps, 16);
    ps += __shfl_xor(ps, 32);
    lsum += ps;

    // PV: o[dt] += P[q][kv] * V[kv][d], two k-slices of 32
#pragma unroll
    for (int ks = 0; ks < 2; ++ks) {
      const int sp = (ks * 4 + g) ^ (c & 7);
      f16x8 pa = *(const f16x8*)(prow + c * 64 + sp * 8);
#pragma unroll
      for (int dt = 0; dt < 4; ++dt) {
        const int d = dt * 16 + c;
        f16x8 vb = *(const f16x8*)(vsb + d * 64 + sp * 8);  // (ks*4+g)^(d&7) == sp
        o[dt] = __builtin_amdgcn_mfma_f32_16x16x32_f16(pa, vb, o[dt], 0, 0, 0);
      }
    }
    cur ^= 1;
  }
#undef STAGE

  // epilogue: inv per q=c -> shuffle to q=g*4+r layout
  const float inv = 1.0f / lsum;
  f16* obase = op + ((size_t)(b * NQ + qt * 64 + wave * 16)) * 384 + h * 64;
#pragma unroll
  for (int r = 0; r < 4; ++r) {
    const float iv = __shfl(inv, g * 4 + r);
#pragma unroll
    for (int dt = 0; dt < 4; ++dt)
      obase[(size_t)(g * 4 + r) * 384 + dt * 16 + c] = (f16)(o[dt][r] * iv);
  }
}

extern "C" void kernel_launch(void* const* d_in, const int* in_sizes, int n_in,
                              void* d_out, int out_size, void* d_ws, size_t ws_size,
                              hipStream_t stream) {
  const float* inputs_q  = (const float*)d_in[0];
  const float* inputs_kv = (const float*)d_in[1];
  const float* out_kern  = (const float*)d_in[2];
  const float* q_dwk = (const float*)d_in[3];
  const float* q_bs  = (const float*)d_in[4];
  const float* q_bb  = (const float*)d_in[5];
  const float* q_bm  = (const float*)d_in[6];
  const float* q_bv  = (const float*)d_in[7];
  const float* q_pwk = (const float*)d_in[8];
  const float* k_dwk = (const float*)d_in[9];
  const float* k_bs  = (const float*)d_in[10];
  const float* k_bb  = (const float*)d_in[11];
  const float* k_bm  = (const float*)d_in[12];
  const float* k_bv  = (const float*)d_in[13];
  const float* k_pwk = (const float*)d_in[14];
  const float* v_dwk = (const float*)d_in[15];
  const float* v_bs  = (const float*)d_in[16];
  const float* v_bb  = (const float*)d_in[17];
  const float* v_bm  = (const float*)d_in[18];
  const float* v_bv  = (const float*)d_in[19];
  const float* v_pwk = (const float*)d_in[20];

  char* wsb = (char*)d_ws;
  f16* qdw = (f16*)(wsb + 0);             // 25088*384 f16
  f16* kdw = (f16*)(wsb + 19267584);      // 6272*384 f16
  f16* vdw = (f16*)(wsb + 24084480);      // 6272*384 f16
  f16* qf  = (f16*)(wsb + 28901376);      // 25088*384 f16
  f16* kf  = (f16*)(wsb + 48168960);      // 6272*384 f16
  f16* vf  = (f16*)(wsb + 52985856);      // 6272*384 f16
  f16* vtp = (f16*)(wsb + 57802752);      // 8*384*784 f16
  f16* of  = (f16*)(wsb + 62619648);      // 25088*384 f16
  f16* wqt = (f16*)(wsb + 81887232);      // 384*384 f16 x4
  f16* wkt = (f16*)(wsb + 82182144);
  f16* wvt = (f16*)(wsb + 82477056);
  f16* wot = (f16*)(wsb + 82771968);

  // 0. weight transpose-convert
  convert_w<<<dim3(12, 12, 4), 256, 0, stream>>>(
      q_pwk, k_pwk, v_pwk, out_kern, wqt, wkt, wvt, wot);
  // 1. depthwise + BN -> f16
  dw_bn_s1<<<9408, 256, 0, stream>>>(inputs_q, q_dwk, q_bs, q_bb, q_bm, q_bv, qdw);
  dw_bn_s2_kv<<<2352, 256, 0, stream>>>(inputs_kv,
      k_dwk, k_bs, k_bb, k_bm, k_bv,
      v_dwk, v_bs, v_bb, v_bm, v_bv,
      kdw, vdw);
  // 2. pointwise GEMMs (q folded with 1/8 * log2e for exp2 softmax)
  gemm_mfma<1><<<dim3(196, 3), 256, 0, stream>>>(qdw, wqt, nullptr, qf, 0.125f * LOG2E);
  gemm_kv<<<dim3(49, 3, 2), 256, 0, stream>>>(kdw, wkt, kf, vdw, wvt, vf);
  // 3. V transpose per batch
  transpose_f16<<<dim3(25, 12, 8), 256, 0, stream>>>(vf, vtp);
  // 4. MFMA attention (swapped layout, stage-ahead dbuf) -> f16 O
  attn_mfma<<<BB * NHD * 49, 256, 0, stream>>>(qf, kf, vtp, of);
  // 5. output projection (MFMA, fp32 out)
  gemm_mfma<0><<<dim3(196, 3), 256, 0, stream>>>(of, wot, (float*)d_out, nullptr, 1.0f);
}